// Round 2
// baseline (93221.631 us; speedup 1.0000x reference)
//
#include <hip/hip_runtime.h>
#include <cstdint>
#include <cstddef>

// ---------------------------------------------------------------------------
// GConvGRU (ChebConv K=3, 2 layers) + readout, for MI355X.
// R2: SpMM = 32-lane group/node, float4 row gather, shfl edge broadcast (MLP).
//     Gates = 4 nodes/block, transposed LDS acts (b128 broadcast), 4x weight reuse.
// ---------------------------------------------------------------------------

__device__ __forceinline__ float sigmoidf_(float x){ return 1.f/(1.f+__expf(-x)); }

// ---------------- preprocessing ----------------

// If edge_index is int64, every odd dword (high word) of the buffer is 0
// (all indices < 50000). If int32, odd dwords are real indices (~0 prob all 0).
__global__ void detect_kernel(const unsigned* __restrict__ buf, int ndw, int* flag){
  int i = blockIdx.x*blockDim.x + threadIdx.x;
  int j = 2*i + 1;
  if (j < ndw && buf[j] != 0u) atomicOr(flag, 1);   // flag=1 -> int32
}

__global__ void convert_kernel(const void* __restrict__ eidx, const float* __restrict__ w,
                               int E, const int* __restrict__ flag,
                               int* __restrict__ row32, int* __restrict__ col32,
                               float* __restrict__ deg, int* __restrict__ cnt){
  int e = blockIdx.x*blockDim.x + threadIdx.x;
  if (e >= E) return;
  int r, c;
  if (*flag){ const int* p = (const int*)eidx; r = p[e]; c = p[E+e]; }
  else { const long long* p = (const long long*)eidx; r = (int)p[e]; c = (int)p[(size_t)E+e]; }
  row32[e] = r; col32[e] = c;
  atomicAdd(deg + r, w[e]);
  atomicAdd(cnt + c, 1);
}

__global__ void node_prep_kernel(const float* __restrict__ deg, float* __restrict__ dinv,
                                 float* __restrict__ dg, int N){
  int n = blockIdx.x*blockDim.x + threadIdx.x;
  if (n >= N) return;
  float d = deg[n];
  if (d > 0.f){ dinv[n] = rsqrtf(d); dg[n] = 0.f; }
  else        { dinv[n] = 0.f;       dg[n] = -1.f; }
}

// Exclusive scan of cnt[N] -> ptr[N+1], single block of 1024 threads.
__global__ void scan_kernel(const int* __restrict__ cnt, int* __restrict__ ptrout, int N){
  __shared__ int s[1024];
  int t = threadIdx.x;
  int chunk = (N + 1023) / 1024;
  int a0 = t*chunk, a1 = min(N, a0 + chunk);
  int sum = 0;
  for (int i = a0; i < a1; ++i) sum += cnt[i];
  s[t] = sum; __syncthreads();
  for (int off = 1; off < 1024; off <<= 1){
    int v = (t >= off) ? s[t-off] : 0;
    __syncthreads();
    s[t] += v;
    __syncthreads();
  }
  int run = (t == 0) ? 0 : s[t-1];
  for (int i = a0; i < a1; ++i){ ptrout[i] = run; run += cnt[i]; }
  if (t == 1023) ptrout[N] = s[1023];
}

__global__ void fill_kernel(const int* __restrict__ row32, const int* __restrict__ col32,
                            const float* __restrict__ w, const float* __restrict__ dinv,
                            const int* __restrict__ ptrv, int* __restrict__ cnt2,
                            int* __restrict__ srcs, float* __restrict__ vals, int E){
  int e = blockIdx.x*blockDim.x + threadIdx.x;
  if (e >= E) return;
  int r = row32[e], c = col32[e];
  int p = ptrv[c] + atomicAdd(cnt2 + c, 1);
  srcs[p] = r;
  vals[p] = -w[e] * dinv[r] * dinv[c];
}

// ---------------- SpMM: y = alpha*(A x + diag*x) + beta*z ----------------
// F=128 floats/node: one 32-lane group per node, float4 per lane (512B row).
// Edge (src,val) loaded coalesced by the group, broadcast via shfl; gathers are
// independent dwordx4 loads -> deep MLP.
__global__ __launch_bounds__(256) void spmm128_kernel(
    const int* __restrict__ ptrv, const int* __restrict__ srcs, const float* __restrict__ vals,
    const float* __restrict__ dg, const float* __restrict__ x, const float* __restrict__ z,
    float* __restrict__ y, int N, float alpha, float beta){
  int t = threadIdx.x;
  int g = t >> 5, lane = t & 31;
  int node = blockIdx.x*8 + g;
  if (node >= N) return;
  int e0 = ptrv[node], e1 = ptrv[node+1];
  const float4* x4 = (const float4*)x;
  float4 acc = make_float4(0.f,0.f,0.f,0.f);
  for (int eb = e0; eb < e1; eb += 32){
    int j = eb + lane;
    int s = 0; float v = 0.f;
    if (j < e1){ s = srcs[j]; v = vals[j]; }
    int m = e1 - eb; if (m > 32) m = 32;
    for (int q = 0; q < m; ++q){
      int   sq = __shfl(s, q, 32);
      float vq = __shfl(v, q, 32);
      float4 xv = x4[(size_t)sq*32 + lane];
      acc.x = fmaf(vq, xv.x, acc.x);
      acc.y = fmaf(vq, xv.y, acc.y);
      acc.z = fmaf(vq, xv.z, acc.z);
      acc.w = fmaf(vq, xv.w, acc.w);
    }
  }
  size_t ii = (size_t)node*32 + lane;
  float dgn = dg[node];
  float4 xi = x4[ii];
  float4 r;
  r.x = alpha*(acc.x + dgn*xi.x);
  r.y = alpha*(acc.y + dgn*xi.y);
  r.z = alpha*(acc.z + dgn*xi.z);
  r.w = alpha*(acc.w + dgn*xi.w);
  if (z){
    float4 zi = ((const float4*)z)[ii];
    r.x = fmaf(beta, zi.x, r.x);
    r.y = fmaf(beta, zi.y, r.y);
    r.z = fmaf(beta, zi.z, r.z);
    r.w = fmaf(beta, zi.w, r.w);
  }
  ((float4*)y)[ii] = r;
}

// F=32 floats/node: 8-lane group per node, float4 per lane.
__global__ __launch_bounds__(256) void spmm32_kernel(
    const int* __restrict__ ptrv, const int* __restrict__ srcs, const float* __restrict__ vals,
    const float* __restrict__ dg, const float* __restrict__ x, const float* __restrict__ z,
    float* __restrict__ y, int N, float alpha, float beta){
  int t = threadIdx.x;
  int g = t >> 3, lane = t & 7;
  int node = blockIdx.x*32 + g;
  if (node >= N) return;
  int e0 = ptrv[node], e1 = ptrv[node+1];
  const float4* x4 = (const float4*)x;
  float4 acc = make_float4(0.f,0.f,0.f,0.f);
  for (int eb = e0; eb < e1; eb += 8){
    int j = eb + lane;
    int s = 0; float v = 0.f;
    if (j < e1){ s = srcs[j]; v = vals[j]; }
    int m = e1 - eb; if (m > 8) m = 8;
    for (int q = 0; q < m; ++q){
      int   sq = __shfl(s, q, 8);
      float vq = __shfl(v, q, 8);
      float4 xv = x4[(size_t)sq*8 + lane];
      acc.x = fmaf(vq, xv.x, acc.x);
      acc.y = fmaf(vq, xv.y, acc.y);
      acc.z = fmaf(vq, xv.z, acc.z);
      acc.w = fmaf(vq, xv.w, acc.w);
    }
  }
  size_t ii = (size_t)node*8 + lane;
  float dgn = dg[node];
  float4 xi = x4[ii];
  float4 r;
  r.x = alpha*(acc.x + dgn*xi.x);
  r.y = alpha*(acc.y + dgn*xi.y);
  r.z = alpha*(acc.z + dgn*xi.z);
  r.w = alpha*(acc.w + dgn*xi.w);
  if (z){
    float4 zi = ((const float4*)z)[ii];
    r.x = fmaf(beta, zi.x, r.x);
    r.y = fmaf(beta, zi.y, r.y);
    r.z = fmaf(beta, zi.z, r.z);
    r.w = fmaf(beta, zi.w, r.w);
  }
  ((float4*)y)[ii] = r;
}

// ---------------- transpose layer-0 input: [B,T,N,8] -> [N, B*8] for step t ----
__global__ void transpose_x_kernel(const float* __restrict__ in, float* __restrict__ out,
                                   int N, int t){
  int idx = blockIdx.x*blockDim.x + threadIdx.x;   // over N*32
  if (idx >= N*32) return;
  int n = idx >> 5; int r = idx & 31; int b = r >> 3; int i = r & 7;
  out[idx] = in[(((size_t)b*12 + t)*N + n)*8 + i];
}

// ---------------- gate A: Z, R, HR, gx2 ----------------
// 4 nodes per block; 128 threads = (b = t>>5, h = t&31). Activations staged
// TRANSPOSED in LDS ([feat][node]) so the 4 nodes' values come from one
// ds_read_b128 broadcast; each weight load is reused 4x.
template<int FIN>
__global__ __launch_bounds__(128) void gateA_kernel(
    const float* __restrict__ xT0, const float* __restrict__ xT1, const float* __restrict__ xT2,
    int xld,
    const float* __restrict__ H, const float* __restrict__ th1, const float* __restrict__ th2,
    const float* __restrict__ Wx, const float* __restrict__ bx,
    const float* __restrict__ Whz, const float* __restrict__ Whr,
    const float* __restrict__ bhz, const float* __restrict__ bhr,
    float* __restrict__ Zb, float* __restrict__ gx2b, float* __restrict__ HRb, int N){
  int n0 = blockIdx.x*4;
  int t = threadIdx.x; int b = t >> 5; int h = t & 31;
  __shared__ float sxT[3][4*FIN][4];
  __shared__ float shT[3][128][4];
  #pragma unroll
  for (int nt = 0; nt < 4; ++nt){
    int node = n0 + nt; if (node >= N) node = n0;
    if (t < 4*FIN){
      sxT[0][t][nt] = xT0[(size_t)node*xld + t];
      sxT[1][t][nt] = xT1[(size_t)node*xld + t];
      sxT[2][t][nt] = xT2[(size_t)node*xld + t];
    }
    shT[0][t][nt] = H  [(size_t)node*128 + t];
    shT[1][t][nt] = th1[(size_t)node*128 + t];
    shT[2][t][nt] = th2[(size_t)node*128 + t];
  }
  __syncthreads();
  float a0[4] = {0,0,0,0}, a1[4] = {0,0,0,0}, a2[4] = {0,0,0,0};
  float az[4] = {0,0,0,0}, ar[4] = {0,0,0,0};
  #pragma unroll
  for (int k = 0; k < 3; ++k){
    #pragma unroll
    for (int i = 0; i < FIN; ++i){
      const float4 xa = *reinterpret_cast<const float4*>(&sxT[k][b*FIN + i][0]);
      float w0 = Wx[((0*3 + k)*FIN + i)*32 + h];
      float w1 = Wx[((1*3 + k)*FIN + i)*32 + h];
      float w2 = Wx[((2*3 + k)*FIN + i)*32 + h];
      a0[0] = fmaf(xa.x, w0, a0[0]); a0[1] = fmaf(xa.y, w0, a0[1]);
      a0[2] = fmaf(xa.z, w0, a0[2]); a0[3] = fmaf(xa.w, w0, a0[3]);
      a1[0] = fmaf(xa.x, w1, a1[0]); a1[1] = fmaf(xa.y, w1, a1[1]);
      a1[2] = fmaf(xa.z, w1, a1[2]); a1[3] = fmaf(xa.w, w1, a1[3]);
      a2[0] = fmaf(xa.x, w2, a2[0]); a2[1] = fmaf(xa.y, w2, a2[1]);
      a2[2] = fmaf(xa.z, w2, a2[2]); a2[3] = fmaf(xa.w, w2, a2[3]);
    }
  }
  #pragma unroll
  for (int k = 0; k < 3; ++k){
    #pragma unroll
    for (int o = 0; o < 32; ++o){
      const float4 ha = *reinterpret_cast<const float4*>(&shT[k][b*32 + o][0]);
      float wz = Whz[(k*32 + o)*32 + h];
      float wr = Whr[(k*32 + o)*32 + h];
      az[0] = fmaf(ha.x, wz, az[0]); az[1] = fmaf(ha.y, wz, az[1]);
      az[2] = fmaf(ha.z, wz, az[2]); az[3] = fmaf(ha.w, wz, az[3]);
      ar[0] = fmaf(ha.x, wr, ar[0]); ar[1] = fmaf(ha.y, wr, ar[1]);
      ar[2] = fmaf(ha.z, wr, ar[2]); ar[3] = fmaf(ha.w, wr, ar[3]);
    }
  }
  float b0 = bx[h], b1 = bx[32+h], b2 = bx[64+h], bz = bhz[h], br = bhr[h];
  #pragma unroll
  for (int nt = 0; nt < 4; ++nt){
    int node = n0 + nt; if (node >= N) break;
    float Z = sigmoidf_(a0[nt] + b0 + az[nt] + bz);
    float R = sigmoidf_(a1[nt] + b1 + ar[nt] + br);
    size_t idx = (size_t)node*128 + t;
    Zb[idx]   = Z;
    gx2b[idx] = a2[nt] + b2;
    HRb[idx]  = shT[0][t][nt] * R;
  }
}

// ---------------- gate B: H = Z*H + (1-Z)*tanh(gx2 + THR.Wh2) ----------------
__global__ __launch_bounds__(128) void gateB_kernel(
    const float* __restrict__ thr0, const float* __restrict__ thr1, const float* __restrict__ thr2,
    const float* __restrict__ Whh, const float* __restrict__ bhh,
    const float* __restrict__ Zb, const float* __restrict__ gx2b,
    float* __restrict__ H, int N){
  int n0 = blockIdx.x*4;
  int t = threadIdx.x; int b = t >> 5; int h = t & 31;
  __shared__ float shT[3][128][4];
  #pragma unroll
  for (int nt = 0; nt < 4; ++nt){
    int node = n0 + nt; if (node >= N) node = n0;
    shT[0][t][nt] = thr0[(size_t)node*128 + t];
    shT[1][t][nt] = thr1[(size_t)node*128 + t];
    shT[2][t][nt] = thr2[(size_t)node*128 + t];
  }
  __syncthreads();
  float ag[4] = {0,0,0,0};
  #pragma unroll
  for (int k = 0; k < 3; ++k){
    #pragma unroll
    for (int o = 0; o < 32; ++o){
      const float4 ha = *reinterpret_cast<const float4*>(&shT[k][b*32 + o][0]);
      float wv = Whh[(k*32 + o)*32 + h];
      ag[0] = fmaf(ha.x, wv, ag[0]); ag[1] = fmaf(ha.y, wv, ag[1]);
      ag[2] = fmaf(ha.z, wv, ag[2]); ag[3] = fmaf(ha.w, wv, ag[3]);
    }
  }
  float bb = bhh[h];
  #pragma unroll
  for (int nt = 0; nt < 4; ++nt){
    int node = n0 + nt; if (node >= N) break;
    size_t idx = (size_t)node*128 + t;
    float Ht = tanhf(gx2b[idx] + ag[nt] + bb);
    float Zv = Zb[idx];
    H[idx] = Zv*H[idx] + (1.f - Zv)*Ht;
  }
}

// ---------------- readout ----------------
__global__ void readout_kernel(const float* __restrict__ H1, const float* __restrict__ muW,
                               const float* __restrict__ mub, const float* __restrict__ sgW,
                               const float* __restrict__ sgb, float* __restrict__ outp, int N){
  int idx = blockIdx.x*blockDim.x + threadIdx.x;   // over 4*N
  if (idx >= 4*N) return;
  int b = idx / N, n = idx - b*N;
  const float* h = H1 + (size_t)n*128 + b*32;
  float m0 = mub[0], m1 = mub[1], s0 = sgb[0], s1 = sgb[1];
  #pragma unroll
  for (int o = 0; o < 32; ++o){
    float v = h[o];
    m0 = fmaf(v, muW[o*2+0], m0);
    m1 = fmaf(v, muW[o*2+1], m1);
    s0 = fmaf(v, sgW[o*2+0], s0);
    s1 = fmaf(v, sgW[o*2+1], s1);
  }
  size_t base = (size_t)(b*N + n)*2;
  outp[base]   = sigmoidf_(m0);
  outp[base+1] = sigmoidf_(m1);
  size_t sb = (size_t)8*N + base;
  outp[sb]   = (s0 > 15.f) ? s0 : log1pf(__expf(s0));
  outp[sb+1] = (s1 > 15.f) ? s1 : log1pf(__expf(s1));
}

__global__ void mean_kernel(const float* __restrict__ H1, float* __restrict__ mixsum, int N){
  int t = threadIdx.x;   // 128 = (b,o)
  int chunk = (N + gridDim.x - 1) / gridDim.x;
  int n0 = blockIdx.x*chunk, n1 = min(N, n0 + chunk);
  float acc = 0.f;
  for (int n = n0; n < n1; ++n) acc += H1[(size_t)n*128 + t];
  atomicAdd(mixsum + t, acc);
}

__global__ void softmax_kernel(const float* __restrict__ mixsum, float* __restrict__ outp,
                               float invN){
  __shared__ float v[128];
  __shared__ float e[128];
  int t = threadIdx.x; int b = t >> 5;
  float m = mixsum[t]*invN;
  v[t] = m; __syncthreads();
  float mx = -1e30f;
  for (int o = 0; o < 32; ++o) mx = fmaxf(mx, v[b*32 + o]);
  float ex = __expf(m - mx);
  e[t] = ex; __syncthreads();
  float s = 0.f;
  for (int o = 0; o < 32; ++o) s += e[b*32 + o];
  outp[t] = ex / s;
}

// ---------------------------------------------------------------------------

extern "C" void kernel_launch(void* const* d_in, const int* in_sizes, int n_in,
                              void* d_out, int out_size, void* d_ws, size_t ws_size,
                              hipStream_t stream){
  const float* in0  = (const float*)d_in[0];
  const void*  eidx = d_in[1];
  const float* ew   = (const float*)d_in[2];
  const float* Wx0  = (const float*)d_in[3];
  const float* Wh0  = (const float*)d_in[4];
  const float* bx0  = (const float*)d_in[5];
  const float* bh0  = (const float*)d_in[6];
  const float* Wx1  = (const float*)d_in[7];
  const float* Wh1  = (const float*)d_in[8];
  const float* bx1  = (const float*)d_in[9];
  const float* bh1  = (const float*)d_in[10];
  const float* muW  = (const float*)d_in[11];
  const float* mub  = (const float*)d_in[12];
  const float* sgW  = (const float*)d_in[13];
  const float* sgb  = (const float*)d_in[14];
  float* outp = (float*)d_out;

  const int N = in_sizes[0] / (4*12*8);
  const int E = in_sizes[1] / 2;

  // ---- carve workspace ----
  char* w = (char*)d_ws;
  size_t off = 0;
  auto alloc = [&](size_t bytes)->void*{
    void* p = w + off;
    off += (bytes + 255) & ~(size_t)255;
    return p;
  };
  int*   row32   = (int*)  alloc((size_t)E*4);
  int*   col32   = (int*)  alloc((size_t)E*4);
  int*   csr_src = (int*)  alloc((size_t)E*4);
  float* csr_val = (float*)alloc((size_t)E*4);
  int*   ptrv    = (int*)  alloc((size_t)(N+1)*4);
  int*   cnt     = (int*)  alloc((size_t)N*4);
  int*   cnt2    = (int*)  alloc((size_t)N*4);
  float* deg     = (float*)alloc((size_t)N*4);
  float* dinv    = (float*)alloc((size_t)N*4);
  float* dgv     = (float*)alloc((size_t)N*4);
  int*   flag    = (int*)  alloc(256);
  float* mixsum  = (float*)alloc(512);
  float* xb0     = (float*)alloc((size_t)N*32*4);
  float* xb1     = (float*)alloc((size_t)N*128*4);
  float* xb2     = (float*)alloc((size_t)N*128*4);
  float* th1     = (float*)alloc((size_t)N*128*4);
  float* th2     = (float*)alloc((size_t)N*128*4);
  float* Zb      = (float*)alloc((size_t)N*128*4);
  float* gx2b    = (float*)alloc((size_t)N*128*4);
  float* HRb     = (float*)alloc((size_t)N*128*4);
  float* H0      = (float*)alloc((size_t)N*128*4);
  float* H1      = (float*)alloc((size_t)N*128*4);

  // ---- zero-init (ws is poisoned 0xAA before each call) ----
  hipMemsetAsync(flag,   0, 4, stream);
  hipMemsetAsync(deg,    0, (size_t)N*4, stream);
  hipMemsetAsync(cnt,    0, (size_t)N*4, stream);
  hipMemsetAsync(cnt2,   0, (size_t)N*4, stream);
  hipMemsetAsync(H0,     0, (size_t)N*128*4, stream);
  hipMemsetAsync(H1,     0, (size_t)N*128*4, stream);
  hipMemsetAsync(mixsum, 0, 512, stream);

  // ---- preprocessing: dtype detect, degrees, CSR build ----
  {
    int ndw = 4096;
    if (ndw > 2*E) ndw = 2*E;
    int nthread = ndw/2 + 1;
    detect_kernel<<<(nthread+255)/256, 256, 0, stream>>>((const unsigned*)eidx, ndw, flag);
  }
  convert_kernel<<<(E+255)/256, 256, 0, stream>>>(eidx, ew, E, flag, row32, col32, deg, cnt);
  node_prep_kernel<<<(N+255)/256, 256, 0, stream>>>(deg, dinv, dgv, N);
  scan_kernel<<<1, 1024, 0, stream>>>(cnt, ptrv, N);
  fill_kernel<<<(E+255)/256, 256, 0, stream>>>(row32, col32, ew, dinv, ptrv, cnt2,
                                               csr_src, csr_val, E);

  const int g128 = (N+7)/8;    // spmm128: 8 nodes / 256 threads
  const int g32  = (N+31)/32;  // spmm32: 32 nodes / 256 threads
  const int gG   = (N+3)/4;    // gates: 4 nodes / 128 threads

  for (int t = 0; t < 12; ++t){
    // ================= layer 0 (Fin=8) =================
    transpose_x_kernel<<<(N*32+255)/256, 256, 0, stream>>>(in0, xb0, N, t);
    spmm32_kernel<<<g32,256,0,stream>>>(ptrv,csr_src,csr_val,dgv, xb0,nullptr,xb1, N, 1.f, 0.f);
    spmm32_kernel<<<g32,256,0,stream>>>(ptrv,csr_src,csr_val,dgv, xb1,xb0,   xb2, N, 2.f,-1.f);
    spmm128_kernel<<<g128,256,0,stream>>>(ptrv,csr_src,csr_val,dgv, H0,nullptr,th1, N, 1.f, 0.f);
    spmm128_kernel<<<g128,256,0,stream>>>(ptrv,csr_src,csr_val,dgv, th1,H0,   th2, N, 2.f,-1.f);
    gateA_kernel<8><<<gG,128,0,stream>>>(xb0,xb1,xb2, 32, H0,th1,th2,
                                         Wx0,bx0, Wh0, Wh0+3072, bh0, bh0+32,
                                         Zb,gx2b,HRb, N);
    spmm128_kernel<<<g128,256,0,stream>>>(ptrv,csr_src,csr_val,dgv, HRb,nullptr,th1, N, 1.f, 0.f);
    spmm128_kernel<<<g128,256,0,stream>>>(ptrv,csr_src,csr_val,dgv, th1,HRb,  th2, N, 2.f,-1.f);
    gateB_kernel<<<gG,128,0,stream>>>(HRb,th1,th2, Wh0+6144, bh0+64, Zb,gx2b, H0, N);

    // ================= layer 1 (Fin=32, input = H0) =================
    spmm128_kernel<<<g128,256,0,stream>>>(ptrv,csr_src,csr_val,dgv, H0,nullptr,xb1, N, 1.f, 0.f);
    spmm128_kernel<<<g128,256,0,stream>>>(ptrv,csr_src,csr_val,dgv, xb1,H0,   xb2, N, 2.f,-1.f);
    spmm128_kernel<<<g128,256,0,stream>>>(ptrv,csr_src,csr_val,dgv, H1,nullptr,th1, N, 1.f, 0.f);
    spmm128_kernel<<<g128,256,0,stream>>>(ptrv,csr_src,csr_val,dgv, th1,H1,   th2, N, 2.f,-1.f);
    gateA_kernel<32><<<gG,128,0,stream>>>(H0,xb1,xb2, 128, H1,th1,th2,
                                          Wx1,bx1, Wh1, Wh1+3072, bh1, bh1+32,
                                          Zb,gx2b,HRb, N);
    spmm128_kernel<<<g128,256,0,stream>>>(ptrv,csr_src,csr_val,dgv, HRb,nullptr,th1, N, 1.f, 0.f);
    spmm128_kernel<<<g128,256,0,stream>>>(ptrv,csr_src,csr_val,dgv, th1,HRb,  th2, N, 2.f,-1.f);
    gateB_kernel<<<gG,128,0,stream>>>(HRb,th1,th2, Wh1+6144, bh1+64, Zb,gx2b, H1, N);
  }

  // ---- readout ----
  readout_kernel<<<(4*N+255)/256, 256, 0, stream>>>(H1, muW, mub, sgW, sgb, outp, N);
  mean_kernel<<<256, 128, 0, stream>>>(H1, mixsum, N);
  softmax_kernel<<<1, 128, 0, stream>>>(mixsum, outp + (size_t)16*N, 1.0f/(float)N);
}

// Round 3
// 18142.390 us; speedup vs baseline: 5.1383x; 5.1383x over previous
//
#include <hip/hip_runtime.h>
#include <cstdint>
#include <cstddef>

// ---------------------------------------------------------------------------
// GConvGRU (ChebConv K=3, 2 layers) + readout, for MI355X.
// R3: R2's grouped-gather SpMM (kept) + R1's known-good gate kernels (reverted:
//     R2's 4-node transposed-LDS gates spilled to scratch, 3.8GB/dispatch).
// ---------------------------------------------------------------------------

__device__ __forceinline__ float sigmoidf_(float x){ return 1.f/(1.f+__expf(-x)); }

// ---------------- preprocessing ----------------

// If edge_index is int64, every odd dword (high word) of the buffer is 0
// (all indices < 50000). If int32, odd dwords are real indices (~0 prob all 0).
__global__ void detect_kernel(const unsigned* __restrict__ buf, int ndw, int* flag){
  int i = blockIdx.x*blockDim.x + threadIdx.x;
  int j = 2*i + 1;
  if (j < ndw && buf[j] != 0u) atomicOr(flag, 1);   // flag=1 -> int32
}

__global__ void convert_kernel(const void* __restrict__ eidx, const float* __restrict__ w,
                               int E, const int* __restrict__ flag,
                               int* __restrict__ row32, int* __restrict__ col32,
                               float* __restrict__ deg, int* __restrict__ cnt){
  int e = blockIdx.x*blockDim.x + threadIdx.x;
  if (e >= E) return;
  int r, c;
  if (*flag){ const int* p = (const int*)eidx; r = p[e]; c = p[E+e]; }
  else { const long long* p = (const long long*)eidx; r = (int)p[e]; c = (int)p[(size_t)E+e]; }
  row32[e] = r; col32[e] = c;
  atomicAdd(deg + r, w[e]);
  atomicAdd(cnt + c, 1);
}

__global__ void node_prep_kernel(const float* __restrict__ deg, float* __restrict__ dinv,
                                 float* __restrict__ dg, int N){
  int n = blockIdx.x*blockDim.x + threadIdx.x;
  if (n >= N) return;
  float d = deg[n];
  if (d > 0.f){ dinv[n] = rsqrtf(d); dg[n] = 0.f; }
  else        { dinv[n] = 0.f;       dg[n] = -1.f; }
}

// Exclusive scan of cnt[N] -> ptr[N+1], single block of 1024 threads.
__global__ void scan_kernel(const int* __restrict__ cnt, int* __restrict__ ptrout, int N){
  __shared__ int s[1024];
  int t = threadIdx.x;
  int chunk = (N + 1023) / 1024;
  int a0 = t*chunk, a1 = min(N, a0 + chunk);
  int sum = 0;
  for (int i = a0; i < a1; ++i) sum += cnt[i];
  s[t] = sum; __syncthreads();
  for (int off = 1; off < 1024; off <<= 1){
    int v = (t >= off) ? s[t-off] : 0;
    __syncthreads();
    s[t] += v;
    __syncthreads();
  }
  int run = (t == 0) ? 0 : s[t-1];
  for (int i = a0; i < a1; ++i){ ptrout[i] = run; run += cnt[i]; }
  if (t == 1023) ptrout[N] = s[1023];
}

__global__ void fill_kernel(const int* __restrict__ row32, const int* __restrict__ col32,
                            const float* __restrict__ w, const float* __restrict__ dinv,
                            const int* __restrict__ ptrv, int* __restrict__ cnt2,
                            int* __restrict__ srcs, float* __restrict__ vals, int E){
  int e = blockIdx.x*blockDim.x + threadIdx.x;
  if (e >= E) return;
  int r = row32[e], c = col32[e];
  int p = ptrv[c] + atomicAdd(cnt2 + c, 1);
  srcs[p] = r;
  vals[p] = -w[e] * dinv[r] * dinv[c];
}

// ---------------- SpMM: y = alpha*(A x + diag*x) + beta*z ----------------
// F=128 floats/node: one 32-lane group per node, float4 per lane (512B row).
// Edge (src,val) loaded coalesced by the group, broadcast via shfl; gathers are
// independent dwordx4 loads -> deep MLP.
__global__ __launch_bounds__(256) void spmm128_kernel(
    const int* __restrict__ ptrv, const int* __restrict__ srcs, const float* __restrict__ vals,
    const float* __restrict__ dg, const float* __restrict__ x, const float* __restrict__ z,
    float* __restrict__ y, int N, float alpha, float beta){
  int t = threadIdx.x;
  int g = t >> 5, lane = t & 31;
  int node = blockIdx.x*8 + g;
  if (node >= N) return;
  int e0 = ptrv[node], e1 = ptrv[node+1];
  const float4* x4 = (const float4*)x;
  float4 acc = make_float4(0.f,0.f,0.f,0.f);
  for (int eb = e0; eb < e1; eb += 32){
    int j = eb + lane;
    int s = 0; float v = 0.f;
    if (j < e1){ s = srcs[j]; v = vals[j]; }
    int m = e1 - eb; if (m > 32) m = 32;
    for (int q = 0; q < m; ++q){
      int   sq = __shfl(s, q, 32);
      float vq = __shfl(v, q, 32);
      float4 xv = x4[(size_t)sq*32 + lane];
      acc.x = fmaf(vq, xv.x, acc.x);
      acc.y = fmaf(vq, xv.y, acc.y);
      acc.z = fmaf(vq, xv.z, acc.z);
      acc.w = fmaf(vq, xv.w, acc.w);
    }
  }
  size_t ii = (size_t)node*32 + lane;
  float dgn = dg[node];
  float4 xi = x4[ii];
  float4 r;
  r.x = alpha*(acc.x + dgn*xi.x);
  r.y = alpha*(acc.y + dgn*xi.y);
  r.z = alpha*(acc.z + dgn*xi.z);
  r.w = alpha*(acc.w + dgn*xi.w);
  if (z){
    float4 zi = ((const float4*)z)[ii];
    r.x = fmaf(beta, zi.x, r.x);
    r.y = fmaf(beta, zi.y, r.y);
    r.z = fmaf(beta, zi.z, r.z);
    r.w = fmaf(beta, zi.w, r.w);
  }
  ((float4*)y)[ii] = r;
}

// F=32 floats/node: 8-lane group per node, float4 per lane.
__global__ __launch_bounds__(256) void spmm32_kernel(
    const int* __restrict__ ptrv, const int* __restrict__ srcs, const float* __restrict__ vals,
    const float* __restrict__ dg, const float* __restrict__ x, const float* __restrict__ z,
    float* __restrict__ y, int N, float alpha, float beta){
  int t = threadIdx.x;
  int g = t >> 3, lane = t & 7;
  int node = blockIdx.x*32 + g;
  if (node >= N) return;
  int e0 = ptrv[node], e1 = ptrv[node+1];
  const float4* x4 = (const float4*)x;
  float4 acc = make_float4(0.f,0.f,0.f,0.f);
  for (int eb = e0; eb < e1; eb += 8){
    int j = eb + lane;
    int s = 0; float v = 0.f;
    if (j < e1){ s = srcs[j]; v = vals[j]; }
    int m = e1 - eb; if (m > 8) m = 8;
    for (int q = 0; q < m; ++q){
      int   sq = __shfl(s, q, 8);
      float vq = __shfl(v, q, 8);
      float4 xv = x4[(size_t)sq*8 + lane];
      acc.x = fmaf(vq, xv.x, acc.x);
      acc.y = fmaf(vq, xv.y, acc.y);
      acc.z = fmaf(vq, xv.z, acc.z);
      acc.w = fmaf(vq, xv.w, acc.w);
    }
  }
  size_t ii = (size_t)node*8 + lane;
  float dgn = dg[node];
  float4 xi = x4[ii];
  float4 r;
  r.x = alpha*(acc.x + dgn*xi.x);
  r.y = alpha*(acc.y + dgn*xi.y);
  r.z = alpha*(acc.z + dgn*xi.z);
  r.w = alpha*(acc.w + dgn*xi.w);
  if (z){
    float4 zi = ((const float4*)z)[ii];
    r.x = fmaf(beta, zi.x, r.x);
    r.y = fmaf(beta, zi.y, r.y);
    r.z = fmaf(beta, zi.z, r.z);
    r.w = fmaf(beta, zi.w, r.w);
  }
  ((float4*)y)[ii] = r;
}

// ---------------- transpose layer-0 input: [B,T,N,8] -> [N, B*8] for step t ----
__global__ void transpose_x_kernel(const float* __restrict__ in, float* __restrict__ out,
                                   int N, int t){
  int idx = blockIdx.x*blockDim.x + threadIdx.x;   // over N*32
  if (idx >= N*32) return;
  int n = idx >> 5; int r = idx & 31; int b = r >> 3; int i = r & 7;
  out[idx] = in[(((size_t)b*12 + t)*N + n)*8 + i];
}

// ---------------- gate A: Z, R, HR, gx2 (R1 version — 36 VGPR, no spill) ----
// One node per block; 128 threads = (b = t/32, h = t%32).
template<int FIN>
__global__ __launch_bounds__(128) void gateA_kernel(
    const float* __restrict__ xT0, const float* __restrict__ xT1, const float* __restrict__ xT2,
    int xld,
    const float* __restrict__ H, const float* __restrict__ th1, const float* __restrict__ th2,
    const float* __restrict__ Wx, const float* __restrict__ bx,
    const float* __restrict__ Whz, const float* __restrict__ Whr,
    const float* __restrict__ bhz, const float* __restrict__ bhr,
    float* __restrict__ Zb, float* __restrict__ gx2b, float* __restrict__ HRb, int N){
  int n = blockIdx.x;
  int t = threadIdx.x; int b = t >> 5; int h = t & 31;
  __shared__ float sx[3][4*FIN];
  __shared__ float sh[3][128];
  for (int i = t; i < 4*FIN; i += 128){
    sx[0][i] = xT0[(size_t)n*xld + i];
    sx[1][i] = xT1[(size_t)n*xld + i];
    sx[2][i] = xT2[(size_t)n*xld + i];
  }
  sh[0][t] = H  [(size_t)n*128 + t];
  sh[1][t] = th1[(size_t)n*128 + t];
  sh[2][t] = th2[(size_t)n*128 + t];
  __syncthreads();
  float g0 = bx[h], g1 = bx[32+h], g2 = bx[64+h];
  #pragma unroll
  for (int k = 0; k < 3; ++k){
    #pragma unroll
    for (int i = 0; i < FIN; ++i){
      float xv = sx[k][b*FIN + i];
      g0 = fmaf(xv, Wx[((0*3 + k)*FIN + i)*32 + h], g0);
      g1 = fmaf(xv, Wx[((1*3 + k)*FIN + i)*32 + h], g1);
      g2 = fmaf(xv, Wx[((2*3 + k)*FIN + i)*32 + h], g2);
    }
  }
  float gz = bhz[h], gr = bhr[h];
  #pragma unroll
  for (int k = 0; k < 3; ++k){
    #pragma unroll
    for (int o = 0; o < 32; ++o){
      float hv = sh[k][b*32 + o];
      gz = fmaf(hv, Whz[(k*32 + o)*32 + h], gz);
      gr = fmaf(hv, Whr[(k*32 + o)*32 + h], gr);
    }
  }
  float Z = sigmoidf_(g0 + gz);
  float R = sigmoidf_(g1 + gr);
  size_t idx = (size_t)n*128 + t;
  Zb[idx]   = Z;
  gx2b[idx] = g2;
  HRb[idx]  = sh[0][t] * R;
}

// ---------------- gate B: H = Z*H + (1-Z)*tanh(gx2 + THR.Wh2) (R1 version) ----
__global__ __launch_bounds__(128) void gateB_kernel(
    const float* __restrict__ thr0, const float* __restrict__ thr1, const float* __restrict__ thr2,
    const float* __restrict__ Whh, const float* __restrict__ bhh,
    const float* __restrict__ Zb, const float* __restrict__ gx2b,
    float* __restrict__ H, int N){
  int n = blockIdx.x;
  int t = threadIdx.x; int b = t >> 5; int h = t & 31;
  __shared__ float sh[3][128];
  sh[0][t] = thr0[(size_t)n*128 + t];
  sh[1][t] = thr1[(size_t)n*128 + t];
  sh[2][t] = thr2[(size_t)n*128 + t];
  __syncthreads();
  float gh = bhh[h];
  #pragma unroll
  for (int k = 0; k < 3; ++k){
    #pragma unroll
    for (int o = 0; o < 32; ++o){
      gh = fmaf(sh[k][b*32 + o], Whh[(k*32 + o)*32 + h], gh);
    }
  }
  size_t idx = (size_t)n*128 + t;
  float Ht = tanhf(gx2b[idx] + gh);
  float Zv = Zb[idx];
  H[idx] = Zv*H[idx] + (1.f - Zv)*Ht;
}

// ---------------- readout ----------------
__global__ void readout_kernel(const float* __restrict__ H1, const float* __restrict__ muW,
                               const float* __restrict__ mub, const float* __restrict__ sgW,
                               const float* __restrict__ sgb, float* __restrict__ outp, int N){
  int idx = blockIdx.x*blockDim.x + threadIdx.x;   // over 4*N
  if (idx >= 4*N) return;
  int b = idx / N, n = idx - b*N;
  const float* h = H1 + (size_t)n*128 + b*32;
  float m0 = mub[0], m1 = mub[1], s0 = sgb[0], s1 = sgb[1];
  #pragma unroll
  for (int o = 0; o < 32; ++o){
    float v = h[o];
    m0 = fmaf(v, muW[o*2+0], m0);
    m1 = fmaf(v, muW[o*2+1], m1);
    s0 = fmaf(v, sgW[o*2+0], s0);
    s1 = fmaf(v, sgW[o*2+1], s1);
  }
  size_t base = (size_t)(b*N + n)*2;
  outp[base]   = sigmoidf_(m0);
  outp[base+1] = sigmoidf_(m1);
  size_t sb = (size_t)8*N + base;
  outp[sb]   = (s0 > 15.f) ? s0 : log1pf(__expf(s0));
  outp[sb+1] = (s1 > 15.f) ? s1 : log1pf(__expf(s1));
}

__global__ void mean_kernel(const float* __restrict__ H1, float* __restrict__ mixsum, int N){
  int t = threadIdx.x;   // 128 = (b,o)
  int chunk = (N + gridDim.x - 1) / gridDim.x;
  int n0 = blockIdx.x*chunk, n1 = min(N, n0 + chunk);
  float acc = 0.f;
  for (int n = n0; n < n1; ++n) acc += H1[(size_t)n*128 + t];
  atomicAdd(mixsum + t, acc);
}

__global__ void softmax_kernel(const float* __restrict__ mixsum, float* __restrict__ outp,
                               float invN){
  __shared__ float v[128];
  __shared__ float e[128];
  int t = threadIdx.x; int b = t >> 5;
  float m = mixsum[t]*invN;
  v[t] = m; __syncthreads();
  float mx = -1e30f;
  for (int o = 0; o < 32; ++o) mx = fmaxf(mx, v[b*32 + o]);
  float ex = __expf(m - mx);
  e[t] = ex; __syncthreads();
  float s = 0.f;
  for (int o = 0; o < 32; ++o) s += e[b*32 + o];
  outp[t] = ex / s;
}

// ---------------------------------------------------------------------------

extern "C" void kernel_launch(void* const* d_in, const int* in_sizes, int n_in,
                              void* d_out, int out_size, void* d_ws, size_t ws_size,
                              hipStream_t stream){
  const float* in0  = (const float*)d_in[0];
  const void*  eidx = d_in[1];
  const float* ew   = (const float*)d_in[2];
  const float* Wx0  = (const float*)d_in[3];
  const float* Wh0  = (const float*)d_in[4];
  const float* bx0  = (const float*)d_in[5];
  const float* bh0  = (const float*)d_in[6];
  const float* Wx1  = (const float*)d_in[7];
  const float* Wh1  = (const float*)d_in[8];
  const float* bx1  = (const float*)d_in[9];
  const float* bh1  = (const float*)d_in[10];
  const float* muW  = (const float*)d_in[11];
  const float* mub  = (const float*)d_in[12];
  const float* sgW  = (const float*)d_in[13];
  const float* sgb  = (const float*)d_in[14];
  float* outp = (float*)d_out;

  const int N = in_sizes[0] / (4*12*8);
  const int E = in_sizes[1] / 2;

  // ---- carve workspace ----
  char* w = (char*)d_ws;
  size_t off = 0;
  auto alloc = [&](size_t bytes)->void*{
    void* p = w + off;
    off += (bytes + 255) & ~(size_t)255;
    return p;
  };
  int*   row32   = (int*)  alloc((size_t)E*4);
  int*   col32   = (int*)  alloc((size_t)E*4);
  int*   csr_src = (int*)  alloc((size_t)E*4);
  float* csr_val = (float*)alloc((size_t)E*4);
  int*   ptrv    = (int*)  alloc((size_t)(N+1)*4);
  int*   cnt     = (int*)  alloc((size_t)N*4);
  int*   cnt2    = (int*)  alloc((size_t)N*4);
  float* deg     = (float*)alloc((size_t)N*4);
  float* dinv    = (float*)alloc((size_t)N*4);
  float* dgv     = (float*)alloc((size_t)N*4);
  int*   flag    = (int*)  alloc(256);
  float* mixsum  = (float*)alloc(512);
  float* xb0     = (float*)alloc((size_t)N*32*4);
  float* xb1     = (float*)alloc((size_t)N*128*4);
  float* xb2     = (float*)alloc((size_t)N*128*4);
  float* th1     = (float*)alloc((size_t)N*128*4);
  float* th2     = (float*)alloc((size_t)N*128*4);
  float* Zb      = (float*)alloc((size_t)N*128*4);
  float* gx2b    = (float*)alloc((size_t)N*128*4);
  float* HRb     = (float*)alloc((size_t)N*128*4);
  float* H0      = (float*)alloc((size_t)N*128*4);
  float* H1      = (float*)alloc((size_t)N*128*4);

  // ---- zero-init (ws is poisoned 0xAA before each call) ----
  hipMemsetAsync(flag,   0, 4, stream);
  hipMemsetAsync(deg,    0, (size_t)N*4, stream);
  hipMemsetAsync(cnt,    0, (size_t)N*4, stream);
  hipMemsetAsync(cnt2,   0, (size_t)N*4, stream);
  hipMemsetAsync(H0,     0, (size_t)N*128*4, stream);
  hipMemsetAsync(H1,     0, (size_t)N*128*4, stream);
  hipMemsetAsync(mixsum, 0, 512, stream);

  // ---- preprocessing: dtype detect, degrees, CSR build ----
  {
    int ndw = 4096;
    if (ndw > 2*E) ndw = 2*E;
    int nthread = ndw/2 + 1;
    detect_kernel<<<(nthread+255)/256, 256, 0, stream>>>((const unsigned*)eidx, ndw, flag);
  }
  convert_kernel<<<(E+255)/256, 256, 0, stream>>>(eidx, ew, E, flag, row32, col32, deg, cnt);
  node_prep_kernel<<<(N+255)/256, 256, 0, stream>>>(deg, dinv, dgv, N);
  scan_kernel<<<1, 1024, 0, stream>>>(cnt, ptrv, N);
  fill_kernel<<<(E+255)/256, 256, 0, stream>>>(row32, col32, ew, dinv, ptrv, cnt2,
                                               csr_src, csr_val, E);

  const int g128 = (N+7)/8;    // spmm128: 8 nodes / 256 threads
  const int g32  = (N+31)/32;  // spmm32: 32 nodes / 256 threads

  for (int t = 0; t < 12; ++t){
    // ================= layer 0 (Fin=8) =================
    transpose_x_kernel<<<(N*32+255)/256, 256, 0, stream>>>(in0, xb0, N, t);
    spmm32_kernel<<<g32,256,0,stream>>>(ptrv,csr_src,csr_val,dgv, xb0,nullptr,xb1, N, 1.f, 0.f);
    spmm32_kernel<<<g32,256,0,stream>>>(ptrv,csr_src,csr_val,dgv, xb1,xb0,   xb2, N, 2.f,-1.f);
    spmm128_kernel<<<g128,256,0,stream>>>(ptrv,csr_src,csr_val,dgv, H0,nullptr,th1, N, 1.f, 0.f);
    spmm128_kernel<<<g128,256,0,stream>>>(ptrv,csr_src,csr_val,dgv, th1,H0,   th2, N, 2.f,-1.f);
    gateA_kernel<8><<<N,128,0,stream>>>(xb0,xb1,xb2, 32, H0,th1,th2,
                                        Wx0,bx0, Wh0, Wh0+3072, bh0, bh0+32,
                                        Zb,gx2b,HRb, N);
    spmm128_kernel<<<g128,256,0,stream>>>(ptrv,csr_src,csr_val,dgv, HRb,nullptr,th1, N, 1.f, 0.f);
    spmm128_kernel<<<g128,256,0,stream>>>(ptrv,csr_src,csr_val,dgv, th1,HRb,  th2, N, 2.f,-1.f);
    gateB_kernel<<<N,128,0,stream>>>(HRb,th1,th2, Wh0+6144, bh0+64, Zb,gx2b, H0, N);

    // ================= layer 1 (Fin=32, input = H0) =================
    spmm128_kernel<<<g128,256,0,stream>>>(ptrv,csr_src,csr_val,dgv, H0,nullptr,xb1, N, 1.f, 0.f);
    spmm128_kernel<<<g128,256,0,stream>>>(ptrv,csr_src,csr_val,dgv, xb1,H0,   xb2, N, 2.f,-1.f);
    spmm128_kernel<<<g128,256,0,stream>>>(ptrv,csr_src,csr_val,dgv, H1,nullptr,th1, N, 1.f, 0.f);
    spmm128_kernel<<<g128,256,0,stream>>>(ptrv,csr_src,csr_val,dgv, th1,H1,   th2, N, 2.f,-1.f);
    gateA_kernel<32><<<N,128,0,stream>>>(H0,xb1,xb2, 128, H1,th1,th2,
                                         Wx1,bx1, Wh1, Wh1+3072, bh1, bh1+32,
                                         Zb,gx2b,HRb, N);
    spmm128_kernel<<<g128,256,0,stream>>>(ptrv,csr_src,csr_val,dgv, HRb,nullptr,th1, N, 1.f, 0.f);
    spmm128_kernel<<<g128,256,0,stream>>>(ptrv,csr_src,csr_val,dgv, th1,HRb,  th2, N, 2.f,-1.f);
    gateB_kernel<<<N,128,0,stream>>>(HRb,th1,th2, Wh1+6144, bh1+64, Zb,gx2b, H1, N);
  }

  // ---- readout ----
  readout_kernel<<<(4*N+255)/256, 256, 0, stream>>>(H1, muW, mub, sgW, sgb, outp, N);
  mean_kernel<<<256, 128, 0, stream>>>(H1, mixsum, N);
  softmax_kernel<<<1, 128, 0, stream>>>(mixsum, outp + (size_t)16*N, 1.0f/(float)N);
}

// Round 4
// 16426.297 us; speedup vs baseline: 5.6751x; 1.1045x over previous
//
#include <hip/hip_runtime.h>
#include <cstdint>
#include <cstddef>

// ---------------------------------------------------------------------------
// GConvGRU (ChebConv K=3, 2 layers) + readout, for MI355X.
// R4: gates rewritten as register-tiled GEMMs (8 rows x few cols per thread,
//     float4 act loads, weights reused 8x, unroll-1 outer K loops -> no spill).
//     SpMM (grouped float4 gather + shfl broadcast) unchanged from R3.
// ---------------------------------------------------------------------------

__device__ __forceinline__ float sigmoidf_(float x){ return 1.f/(1.f+__expf(-x)); }

// ---------------- preprocessing ----------------

// If edge_index is int64, every odd dword (high word) of the buffer is 0
// (all indices < 50000). If int32, odd dwords are real indices (~0 prob all 0).
__global__ void detect_kernel(const unsigned* __restrict__ buf, int ndw, int* flag){
  int i = blockIdx.x*blockDim.x + threadIdx.x;
  int j = 2*i + 1;
  if (j < ndw && buf[j] != 0u) atomicOr(flag, 1);   // flag=1 -> int32
}

__global__ void convert_kernel(const void* __restrict__ eidx, const float* __restrict__ w,
                               int E, const int* __restrict__ flag,
                               int* __restrict__ row32, int* __restrict__ col32,
                               float* __restrict__ deg, int* __restrict__ cnt){
  int e = blockIdx.x*blockDim.x + threadIdx.x;
  if (e >= E) return;
  int r, c;
  if (*flag){ const int* p = (const int*)eidx; r = p[e]; c = p[E+e]; }
  else { const long long* p = (const long long*)eidx; r = (int)p[e]; c = (int)p[(size_t)E+e]; }
  row32[e] = r; col32[e] = c;
  atomicAdd(deg + r, w[e]);
  atomicAdd(cnt + c, 1);
}

__global__ void node_prep_kernel(const float* __restrict__ deg, float* __restrict__ dinv,
                                 float* __restrict__ dg, int N){
  int n = blockIdx.x*blockDim.x + threadIdx.x;
  if (n >= N) return;
  float d = deg[n];
  if (d > 0.f){ dinv[n] = rsqrtf(d); dg[n] = 0.f; }
  else        { dinv[n] = 0.f;       dg[n] = -1.f; }
}

// Exclusive scan of cnt[N] -> ptr[N+1], single block of 1024 threads.
__global__ void scan_kernel(const int* __restrict__ cnt, int* __restrict__ ptrout, int N){
  __shared__ int s[1024];
  int t = threadIdx.x;
  int chunk = (N + 1023) / 1024;
  int a0 = t*chunk, a1 = min(N, a0 + chunk);
  int sum = 0;
  for (int i = a0; i < a1; ++i) sum += cnt[i];
  s[t] = sum; __syncthreads();
  for (int off = 1; off < 1024; off <<= 1){
    int v = (t >= off) ? s[t-off] : 0;
    __syncthreads();
    s[t] += v;
    __syncthreads();
  }
  int run = (t == 0) ? 0 : s[t-1];
  for (int i = a0; i < a1; ++i){ ptrout[i] = run; run += cnt[i]; }
  if (t == 1023) ptrout[N] = s[1023];
}

__global__ void fill_kernel(const int* __restrict__ row32, const int* __restrict__ col32,
                            const float* __restrict__ w, const float* __restrict__ dinv,
                            const int* __restrict__ ptrv, int* __restrict__ cnt2,
                            int* __restrict__ srcs, float* __restrict__ vals, int E){
  int e = blockIdx.x*blockDim.x + threadIdx.x;
  if (e >= E) return;
  int r = row32[e], c = col32[e];
  int p = ptrv[c] + atomicAdd(cnt2 + c, 1);
  srcs[p] = r;
  vals[p] = -w[e] * dinv[r] * dinv[c];
}

// ---------------- SpMM: y = alpha*(A x + diag*x) + beta*z ----------------
// F=128 floats/node: one 32-lane group per node, float4 per lane (512B row).
__global__ __launch_bounds__(256) void spmm128_kernel(
    const int* __restrict__ ptrv, const int* __restrict__ srcs, const float* __restrict__ vals,
    const float* __restrict__ dg, const float* __restrict__ x, const float* __restrict__ z,
    float* __restrict__ y, int N, float alpha, float beta){
  int t = threadIdx.x;
  int g = t >> 5, lane = t & 31;
  int node = blockIdx.x*8 + g;
  if (node >= N) return;
  int e0 = ptrv[node], e1 = ptrv[node+1];
  const float4* x4 = (const float4*)x;
  float4 acc = make_float4(0.f,0.f,0.f,0.f);
  for (int eb = e0; eb < e1; eb += 32){
    int j = eb + lane;
    int s = 0; float v = 0.f;
    if (j < e1){ s = srcs[j]; v = vals[j]; }
    int m = e1 - eb; if (m > 32) m = 32;
    for (int q = 0; q < m; ++q){
      int   sq = __shfl(s, q, 32);
      float vq = __shfl(v, q, 32);
      float4 xv = x4[(size_t)sq*32 + lane];
      acc.x = fmaf(vq, xv.x, acc.x);
      acc.y = fmaf(vq, xv.y, acc.y);
      acc.z = fmaf(vq, xv.z, acc.z);
      acc.w = fmaf(vq, xv.w, acc.w);
    }
  }
  size_t ii = (size_t)node*32 + lane;
  float dgn = dg[node];
  float4 xi = x4[ii];
  float4 r;
  r.x = alpha*(acc.x + dgn*xi.x);
  r.y = alpha*(acc.y + dgn*xi.y);
  r.z = alpha*(acc.z + dgn*xi.z);
  r.w = alpha*(acc.w + dgn*xi.w);
  if (z){
    float4 zi = ((const float4*)z)[ii];
    r.x = fmaf(beta, zi.x, r.x);
    r.y = fmaf(beta, zi.y, r.y);
    r.z = fmaf(beta, zi.z, r.z);
    r.w = fmaf(beta, zi.w, r.w);
  }
  ((float4*)y)[ii] = r;
}

// F=32 floats/node: 8-lane group per node, float4 per lane.
__global__ __launch_bounds__(256) void spmm32_kernel(
    const int* __restrict__ ptrv, const int* __restrict__ srcs, const float* __restrict__ vals,
    const float* __restrict__ dg, const float* __restrict__ x, const float* __restrict__ z,
    float* __restrict__ y, int N, float alpha, float beta){
  int t = threadIdx.x;
  int g = t >> 3, lane = t & 7;
  int node = blockIdx.x*32 + g;
  if (node >= N) return;
  int e0 = ptrv[node], e1 = ptrv[node+1];
  const float4* x4 = (const float4*)x;
  float4 acc = make_float4(0.f,0.f,0.f,0.f);
  for (int eb = e0; eb < e1; eb += 8){
    int j = eb + lane;
    int s = 0; float v = 0.f;
    if (j < e1){ s = srcs[j]; v = vals[j]; }
    int m = e1 - eb; if (m > 8) m = 8;
    for (int q = 0; q < m; ++q){
      int   sq = __shfl(s, q, 8);
      float vq = __shfl(v, q, 8);
      float4 xv = x4[(size_t)sq*8 + lane];
      acc.x = fmaf(vq, xv.x, acc.x);
      acc.y = fmaf(vq, xv.y, acc.y);
      acc.z = fmaf(vq, xv.z, acc.z);
      acc.w = fmaf(vq, xv.w, acc.w);
    }
  }
  size_t ii = (size_t)node*8 + lane;
  float dgn = dg[node];
  float4 xi = x4[ii];
  float4 r;
  r.x = alpha*(acc.x + dgn*xi.x);
  r.y = alpha*(acc.y + dgn*xi.y);
  r.z = alpha*(acc.z + dgn*xi.z);
  r.w = alpha*(acc.w + dgn*xi.w);
  if (z){
    float4 zi = ((const float4*)z)[ii];
    r.x = fmaf(beta, zi.x, r.x);
    r.y = fmaf(beta, zi.y, r.y);
    r.z = fmaf(beta, zi.z, r.z);
    r.w = fmaf(beta, zi.w, r.w);
  }
  ((float4*)y)[ii] = r;
}

// ---------------- transpose layer-0 input: [B,T,N,8] -> [N, B*8] for step t ----
__global__ void transpose_x_kernel(const float* __restrict__ in, float* __restrict__ out,
                                   int N, int t){
  int idx = blockIdx.x*blockDim.x + threadIdx.x;   // over N*32
  if (idx >= N*32) return;
  int n = idx >> 5; int r = idx & 31; int b = r >> 3; int i = r & 7;
  out[idx] = in[(((size_t)b*12 + t)*N + n)*8 + i];
}

// ---------------- gate A (register-tiled GEMM) ----------------
// Rows = (n,b) pairs, M = 4N. Acts are contiguous [M x F] (row = rr*F).
// Block 256 = 32 h-cols x 8 row-groups; thread: 8 rows x (3 x-gates + 2 h-gates).
// Outer K loops deliberately unroll(1) to bound live registers (R2 lesson).
template<int FIN>
__global__ __launch_bounds__(256) void gateA_kernel(
    const float* __restrict__ x0, const float* __restrict__ x1, const float* __restrict__ x2,
    const float* __restrict__ h0, const float* __restrict__ h1, const float* __restrict__ h2,
    const float* __restrict__ Wx, const float* __restrict__ bx,
    const float* __restrict__ Wh, const float* __restrict__ bh,
    float* __restrict__ Zb, float* __restrict__ gx2b, float* __restrict__ HRb, int M){
  int t = threadIdx.x;
  int h = t & 31, ty = t >> 5;
  int row0 = blockIdx.x*64 + ty*8;
  if (row0 >= M) return;
  bool full = (row0 + 8 <= M);

  float ag0[8]={0,0,0,0,0,0,0,0}, ag1[8]={0,0,0,0,0,0,0,0}, ag2[8]={0,0,0,0,0,0,0,0};
  float az[8]={0,0,0,0,0,0,0,0}, ar[8]={0,0,0,0,0,0,0,0};

  const float* xm[3] = {x0, x1, x2};
  const float* hm[3] = {h0, h1, h2};
  const int gstride = 3*FIN*32;

  // ---- x-part: ag[g] += sum_k3 sum_i x_k3[row][i] * Wx[g][k3][i][h] ----
  #pragma unroll 1
  for (int k3 = 0; k3 < 3; ++k3){
    const float* Ak = xm[k3];
    const float* wb = Wx + k3*FIN*32 + h;
    #pragma unroll 1
    for (int k = 0; k < FIN; k += 4){
      float4 a4[8];
      #pragma unroll
      for (int r = 0; r < 8; ++r){
        int rr = row0 + r; if (!full && rr >= M) rr = M-1;
        a4[r] = *reinterpret_cast<const float4*>(Ak + (size_t)rr*FIN + k);
      }
      #pragma unroll
      for (int kk = 0; kk < 4; ++kk){
        float w0 = wb[(k+kk)*32];
        float w1 = wb[(size_t)gstride   + (k+kk)*32];
        float w2 = wb[(size_t)gstride*2 + (k+kk)*32];
        #pragma unroll
        for (int r = 0; r < 8; ++r){
          float av = reinterpret_cast<const float*>(&a4[r])[kk];
          ag0[r] = fmaf(av, w0, ag0[r]);
          ag1[r] = fmaf(av, w1, ag1[r]);
          ag2[r] = fmaf(av, w2, ag2[r]);
        }
      }
    }
  }

  // ---- h-part: az/ar += sum_k3 sum_o h_k3[row][o] * Wh[{z,r}][k3][o][h] ----
  #pragma unroll 1
  for (int k3 = 0; k3 < 3; ++k3){
    const float* Ak = hm[k3];
    const float* wbz = Wh + k3*1024 + h;          // Wh[0][k3][o][h]
    #pragma unroll 1
    for (int k = 0; k < 32; k += 4){
      float4 a4[8];
      #pragma unroll
      for (int r = 0; r < 8; ++r){
        int rr = row0 + r; if (!full && rr >= M) rr = M-1;
        a4[r] = *reinterpret_cast<const float4*>(Ak + (size_t)rr*32 + k);
      }
      #pragma unroll
      for (int kk = 0; kk < 4; ++kk){
        float wz = wbz[(k+kk)*32];
        float wr = wbz[3072 + (k+kk)*32];
        #pragma unroll
        for (int r = 0; r < 8; ++r){
          float av = reinterpret_cast<const float*>(&a4[r])[kk];
          az[r] = fmaf(av, wz, az[r]);
          ar[r] = fmaf(av, wr, ar[r]);
        }
      }
    }
  }

  float b0 = bx[h], b1 = bx[32+h], b2 = bx[64+h];
  float bz = bh[h], br = bh[32+h];
  #pragma unroll
  for (int r = 0; r < 8; ++r){
    int rr = row0 + r; if (rr >= M) break;
    float Z = sigmoidf_(ag0[r] + b0 + az[r] + bz);
    float R = sigmoidf_(ag1[r] + b1 + ar[r] + br);
    size_t ix = (size_t)rr*32 + h;
    Zb[ix]   = Z;
    gx2b[ix] = ag2[r] + b2;
    HRb[ix]  = h0[ix] * R;
  }
}

// ---------------- gate B: H = Z*H + (1-Z)*tanh(gx2 + THR.Wh2 + bh2) ----------
__global__ __launch_bounds__(256) void gateB_kernel(
    const float* __restrict__ p0, const float* __restrict__ p1, const float* __restrict__ p2,
    const float* __restrict__ Whh, const float* __restrict__ bhh,
    const float* __restrict__ Zb, const float* __restrict__ gx2b,
    float* __restrict__ H, int M){
  int t = threadIdx.x;
  int h = t & 31, ty = t >> 5;
  int row0 = blockIdx.x*64 + ty*8;
  if (row0 >= M) return;
  bool full = (row0 + 8 <= M);
  float acc[8]={0,0,0,0,0,0,0,0};
  const float* pm[3] = {p0, p1, p2};
  #pragma unroll 1
  for (int k3 = 0; k3 < 3; ++k3){
    const float* Ak = pm[k3];
    const float* wb = Whh + k3*1024 + h;
    #pragma unroll 1
    for (int k = 0; k < 32; k += 4){
      float4 a4[8];
      #pragma unroll
      for (int r = 0; r < 8; ++r){
        int rr = row0 + r; if (!full && rr >= M) rr = M-1;
        a4[r] = *reinterpret_cast<const float4*>(Ak + (size_t)rr*32 + k);
      }
      #pragma unroll
      for (int kk = 0; kk < 4; ++kk){
        float wv = wb[(k+kk)*32];
        #pragma unroll
        for (int r = 0; r < 8; ++r){
          float av = reinterpret_cast<const float*>(&a4[r])[kk];
          acc[r] = fmaf(av, wv, acc[r]);
        }
      }
    }
  }
  float bb = bhh[h];
  #pragma unroll
  for (int r = 0; r < 8; ++r){
    int rr = row0 + r; if (rr >= M) break;
    size_t ix = (size_t)rr*32 + h;
    float Ht = tanhf(gx2b[ix] + acc[r] + bb);
    float Zv = Zb[ix];
    H[ix] = Zv*H[ix] + (1.f - Zv)*Ht;
  }
}

// ---------------- readout ----------------
__global__ void readout_kernel(const float* __restrict__ H1, const float* __restrict__ muW,
                               const float* __restrict__ mub, const float* __restrict__ sgW,
                               const float* __restrict__ sgb, float* __restrict__ outp, int N){
  int idx = blockIdx.x*blockDim.x + threadIdx.x;   // over 4*N
  if (idx >= 4*N) return;
  int b = idx / N, n = idx - b*N;
  const float* h = H1 + (size_t)n*128 + b*32;
  float m0 = mub[0], m1 = mub[1], s0 = sgb[0], s1 = sgb[1];
  #pragma unroll
  for (int o = 0; o < 32; ++o){
    float v = h[o];
    m0 = fmaf(v, muW[o*2+0], m0);
    m1 = fmaf(v, muW[o*2+1], m1);
    s0 = fmaf(v, sgW[o*2+0], s0);
    s1 = fmaf(v, sgW[o*2+1], s1);
  }
  size_t base = (size_t)(b*N + n)*2;
  outp[base]   = sigmoidf_(m0);
  outp[base+1] = sigmoidf_(m1);
  size_t sb = (size_t)8*N + base;
  outp[sb]   = (s0 > 15.f) ? s0 : log1pf(__expf(s0));
  outp[sb+1] = (s1 > 15.f) ? s1 : log1pf(__expf(s1));
}

__global__ void mean_kernel(const float* __restrict__ H1, float* __restrict__ mixsum, int N){
  int t = threadIdx.x;   // 128 = (b,o)
  int chunk = (N + gridDim.x - 1) / gridDim.x;
  int n0 = blockIdx.x*chunk, n1 = min(N, n0 + chunk);
  float acc = 0.f;
  for (int n = n0; n < n1; ++n) acc += H1[(size_t)n*128 + t];
  atomicAdd(mixsum + t, acc);
}

__global__ void softmax_kernel(const float* __restrict__ mixsum, float* __restrict__ outp,
                               float invN){
  __shared__ float v[128];
  __shared__ float e[128];
  int t = threadIdx.x; int b = t >> 5;
  float m = mixsum[t]*invN;
  v[t] = m; __syncthreads();
  float mx = -1e30f;
  for (int o = 0; o < 32; ++o) mx = fmaxf(mx, v[b*32 + o]);
  float ex = __expf(m - mx);
  e[t] = ex; __syncthreads();
  float s = 0.f;
  for (int o = 0; o < 32; ++o) s += e[b*32 + o];
  outp[t] = ex / s;
}

// ---------------------------------------------------------------------------

extern "C" void kernel_launch(void* const* d_in, const int* in_sizes, int n_in,
                              void* d_out, int out_size, void* d_ws, size_t ws_size,
                              hipStream_t stream){
  const float* in0  = (const float*)d_in[0];
  const void*  eidx = d_in[1];
  const float* ew   = (const float*)d_in[2];
  const float* Wx0  = (const float*)d_in[3];
  const float* Wh0  = (const float*)d_in[4];
  const float* bx0  = (const float*)d_in[5];
  const float* bh0  = (const float*)d_in[6];
  const float* Wx1  = (const float*)d_in[7];
  const float* Wh1  = (const float*)d_in[8];
  const float* bx1  = (const float*)d_in[9];
  const float* bh1  = (const float*)d_in[10];
  const float* muW  = (const float*)d_in[11];
  const float* mub  = (const float*)d_in[12];
  const float* sgW  = (const float*)d_in[13];
  const float* sgb  = (const float*)d_in[14];
  float* outp = (float*)d_out;

  const int N = in_sizes[0] / (4*12*8);
  const int E = in_sizes[1] / 2;
  const int M = 4*N;

  // ---- carve workspace ----
  char* w = (char*)d_ws;
  size_t off = 0;
  auto alloc = [&](size_t bytes)->void*{
    void* p = w + off;
    off += (bytes + 255) & ~(size_t)255;
    return p;
  };
  int*   row32   = (int*)  alloc((size_t)E*4);
  int*   col32   = (int*)  alloc((size_t)E*4);
  int*   csr_src = (int*)  alloc((size_t)E*4);
  float* csr_val = (float*)alloc((size_t)E*4);
  int*   ptrv    = (int*)  alloc((size_t)(N+1)*4);
  int*   cnt     = (int*)  alloc((size_t)N*4);
  int*   cnt2    = (int*)  alloc((size_t)N*4);
  float* deg     = (float*)alloc((size_t)N*4);
  float* dinv    = (float*)alloc((size_t)N*4);
  float* dgv     = (float*)alloc((size_t)N*4);
  int*   flag    = (int*)  alloc(256);
  float* mixsum  = (float*)alloc(512);
  float* xb0     = (float*)alloc((size_t)N*32*4);
  float* xb1     = (float*)alloc((size_t)N*128*4);
  float* xb2     = (float*)alloc((size_t)N*128*4);
  float* th1     = (float*)alloc((size_t)N*128*4);
  float* th2     = (float*)alloc((size_t)N*128*4);
  float* Zb      = (float*)alloc((size_t)N*128*4);
  float* gx2b    = (float*)alloc((size_t)N*128*4);
  float* HRb     = (float*)alloc((size_t)N*128*4);
  float* H0      = (float*)alloc((size_t)N*128*4);
  float* H1      = (float*)alloc((size_t)N*128*4);

  // ---- zero-init (ws is poisoned 0xAA before each call) ----
  hipMemsetAsync(flag,   0, 4, stream);
  hipMemsetAsync(deg,    0, (size_t)N*4, stream);
  hipMemsetAsync(cnt,    0, (size_t)N*4, stream);
  hipMemsetAsync(cnt2,   0, (size_t)N*4, stream);
  hipMemsetAsync(H0,     0, (size_t)N*128*4, stream);
  hipMemsetAsync(H1,     0, (size_t)N*128*4, stream);
  hipMemsetAsync(mixsum, 0, 512, stream);

  // ---- preprocessing: dtype detect, degrees, CSR build ----
  {
    int ndw = 4096;
    if (ndw > 2*E) ndw = 2*E;
    int nthread = ndw/2 + 1;
    detect_kernel<<<(nthread+255)/256, 256, 0, stream>>>((const unsigned*)eidx, ndw, flag);
  }
  convert_kernel<<<(E+255)/256, 256, 0, stream>>>(eidx, ew, E, flag, row32, col32, deg, cnt);
  node_prep_kernel<<<(N+255)/256, 256, 0, stream>>>(deg, dinv, dgv, N);
  scan_kernel<<<1, 1024, 0, stream>>>(cnt, ptrv, N);
  fill_kernel<<<(E+255)/256, 256, 0, stream>>>(row32, col32, ew, dinv, ptrv, cnt2,
                                               csr_src, csr_val, E);

  const int g128 = (N+7)/8;    // spmm128: 8 nodes / 256 threads
  const int g32  = (N+31)/32;  // spmm32: 32 nodes / 256 threads
  const int gG   = (M+63)/64;  // gates: 64 rows / 256 threads

  for (int t = 0; t < 12; ++t){
    // ================= layer 0 (Fin=8) =================
    transpose_x_kernel<<<(N*32+255)/256, 256, 0, stream>>>(in0, xb0, N, t);
    spmm32_kernel<<<g32,256,0,stream>>>(ptrv,csr_src,csr_val,dgv, xb0,nullptr,xb1, N, 1.f, 0.f);
    spmm32_kernel<<<g32,256,0,stream>>>(ptrv,csr_src,csr_val,dgv, xb1,xb0,   xb2, N, 2.f,-1.f);
    spmm128_kernel<<<g128,256,0,stream>>>(ptrv,csr_src,csr_val,dgv, H0,nullptr,th1, N, 1.f, 0.f);
    spmm128_kernel<<<g128,256,0,stream>>>(ptrv,csr_src,csr_val,dgv, th1,H0,   th2, N, 2.f,-1.f);
    gateA_kernel<8><<<gG,256,0,stream>>>(xb0,xb1,xb2, H0,th1,th2,
                                         Wx0,bx0, Wh0,bh0, Zb,gx2b,HRb, M);
    spmm128_kernel<<<g128,256,0,stream>>>(ptrv,csr_src,csr_val,dgv, HRb,nullptr,th1, N, 1.f, 0.f);
    spmm128_kernel<<<g128,256,0,stream>>>(ptrv,csr_src,csr_val,dgv, th1,HRb,  th2, N, 2.f,-1.f);
    gateB_kernel<<<gG,256,0,stream>>>(HRb,th1,th2, Wh0+6144, bh0+64, Zb,gx2b, H0, M);

    // ================= layer 1 (Fin=32, input = H0) =================
    spmm128_kernel<<<g128,256,0,stream>>>(ptrv,csr_src,csr_val,dgv, H0,nullptr,xb1, N, 1.f, 0.f);
    spmm128_kernel<<<g128,256,0,stream>>>(ptrv,csr_src,csr_val,dgv, xb1,H0,   xb2, N, 2.f,-1.f);
    spmm128_kernel<<<g128,256,0,stream>>>(ptrv,csr_src,csr_val,dgv, H1,nullptr,th1, N, 1.f, 0.f);
    spmm128_kernel<<<g128,256,0,stream>>>(ptrv,csr_src,csr_val,dgv, th1,H1,   th2, N, 2.f,-1.f);
    gateA_kernel<32><<<gG,256,0,stream>>>(H0,xb1,xb2, H1,th1,th2,
                                          Wx1,bx1, Wh1,bh1, Zb,gx2b,HRb, M);
    spmm128_kernel<<<g128,256,0,stream>>>(ptrv,csr_src,csr_val,dgv, HRb,nullptr,th1, N, 1.f, 0.f);
    spmm128_kernel<<<g128,256,0,stream>>>(ptrv,csr_src,csr_val,dgv, th1,HRb,  th2, N, 2.f,-1.f);
    gateB_kernel<<<gG,256,0,stream>>>(HRb,th1,th2, Wh1+6144, bh1+64, Zb,gx2b, H1, M);
  }

  // ---- readout ----
  readout_kernel<<<(4*N+255)/256, 256, 0, stream>>>(H1, muW, mub, sgW, sgb, outp, N);
  mean_kernel<<<256, 128, 0, stream>>>(H1, mixsum, N);
  softmax_kernel<<<1, 128, 0, stream>>>(mixsum, outp + (size_t)16*N, 1.0f/(float)N);
}

// Round 5
// 14824.055 us; speedup vs baseline: 6.2885x; 1.1081x over previous
//
#include <hip/hip_runtime.h>
#include <cstdint>
#include <cstddef>

// ---------------------------------------------------------------------------
// GConvGRU (ChebConv K=3, 2 layers) + readout, for MI355X.
// R5: (1) CSR rows padded to multiple of 8 -> inner gather loop unrolled x8
//     (8 loads in flight/wave; R4 spmm was 1-load-in-flight, VALUBusy 2%).
//     (2) gateB fused into the 2nd HR-basis spmm pass (p0/p1/p2 already in
//     registers at the epilogue; LDS stage + per-lane 4-col GEMM).
//     gateA register-tiled GEMM unchanged from R4 (215us, no spill).
// ---------------------------------------------------------------------------

__device__ __forceinline__ float sigmoidf_(float x){ return 1.f/(1.f+__expf(-x)); }

// ---------------- preprocessing ----------------

// If edge_index is int64, every odd dword (high word) of the buffer is 0
// (all indices < 50000). If int32, odd dwords are real indices (~0 prob all 0).
__global__ void detect_kernel(const unsigned* __restrict__ buf, int ndw, int* flag){
  int i = blockIdx.x*blockDim.x + threadIdx.x;
  int j = 2*i + 1;
  if (j < ndw && buf[j] != 0u) atomicOr(flag, 1);   // flag=1 -> int32
}

__global__ void convert_kernel(const void* __restrict__ eidx, const float* __restrict__ w,
                               int E, const int* __restrict__ flag,
                               int* __restrict__ row32, int* __restrict__ col32,
                               float* __restrict__ deg, int* __restrict__ cnt){
  int e = blockIdx.x*blockDim.x + threadIdx.x;
  if (e >= E) return;
  int r, c;
  if (*flag){ const int* p = (const int*)eidx; r = p[e]; c = p[E+e]; }
  else { const long long* p = (const long long*)eidx; r = (int)p[e]; c = (int)p[(size_t)E+e]; }
  row32[e] = r; col32[e] = c;
  atomicAdd(deg + r, w[e]);
  atomicAdd(cnt + c, 1);
}

__global__ void node_prep_kernel(const float* __restrict__ deg, float* __restrict__ dinv,
                                 float* __restrict__ dg, int N){
  int n = blockIdx.x*blockDim.x + threadIdx.x;
  if (n >= N) return;
  float d = deg[n];
  if (d > 0.f){ dinv[n] = rsqrtf(d); dg[n] = 0.f; }
  else        { dinv[n] = 0.f;       dg[n] = -1.f; }
}

// Exclusive scan of PADDED counts ((cnt+7)&~7) -> ptr[N+1]. 1 block, 1024 thr.
__global__ void scan_kernel(const int* __restrict__ cnt, int* __restrict__ ptrout, int N){
  __shared__ int s[1024];
  int t = threadIdx.x;
  int chunk = (N + 1023) / 1024;
  int a0 = t*chunk, a1 = min(N, a0 + chunk);
  int sum = 0;
  for (int i = a0; i < a1; ++i) sum += (cnt[i]+7)&~7;
  s[t] = sum; __syncthreads();
  for (int off = 1; off < 1024; off <<= 1){
    int v = (t >= off) ? s[t-off] : 0;
    __syncthreads();
    s[t] += v;
    __syncthreads();
  }
  int run = (t == 0) ? 0 : s[t-1];
  for (int i = a0; i < a1; ++i){ ptrout[i] = run; run += (cnt[i]+7)&~7; }
  if (t == 1023) ptrout[N] = s[1023];
}

__global__ void fill_kernel(const int* __restrict__ row32, const int* __restrict__ col32,
                            const float* __restrict__ w, const float* __restrict__ dinv,
                            const int* __restrict__ ptrv, int* __restrict__ cnt2,
                            int* __restrict__ srcs, float* __restrict__ vals, int E){
  int e = blockIdx.x*blockDim.x + threadIdx.x;
  if (e >= E) return;
  int r = row32[e], c = col32[e];
  int p = ptrv[c] + atomicAdd(cnt2 + c, 1);
  srcs[p] = r;
  vals[p] = -w[e] * dinv[r] * dinv[c];
}

// Fill pad slots [cnt[n], ptr[n+1]-ptr[n]) with (src=n, val=0).
__global__ void pad_kernel(const int* __restrict__ cnt, const int* __restrict__ ptrv,
                           int* __restrict__ srcs, float* __restrict__ vals, int N){
  int n = blockIdx.x*blockDim.x + threadIdx.x;
  if (n >= N) return;
  int base = ptrv[n];
  int real = cnt[n];
  int padded = ptrv[n+1] - base;
  for (int j = real; j < padded; ++j){ srcs[base+j] = n; vals[base+j] = 0.f; }
}

// ---------------- SpMM: y = alpha*(A x + diag*x) + beta*z ----------------
// F=128 floats/node: one 32-lane group per node, float4 per lane (512B row).
// Edge count per node is a multiple of 8 -> inner loop unrolled x8 (8 gathers
// in flight). Edge (s,v) loaded by lanes 0..7 of the group, shfl-broadcast.
__global__ __launch_bounds__(256) void spmm128_kernel(
    const int* __restrict__ ptrv, const int* __restrict__ srcs, const float* __restrict__ vals,
    const float* __restrict__ dg, const float* __restrict__ x, const float* __restrict__ z,
    float* __restrict__ y, int N, float alpha, float beta){
  int t = threadIdx.x;
  int g = t >> 5, lane = t & 31;
  int node = blockIdx.x*8 + g;
  if (node >= N) return;
  int e0 = ptrv[node], e1 = ptrv[node+1];
  const float4* x4 = (const float4*)x;
  float4 acc = make_float4(0.f,0.f,0.f,0.f);
  for (int eb = e0; eb < e1; eb += 8){
    int j = eb + (lane & 7);
    int s = srcs[j]; float v = vals[j];
    #pragma unroll
    for (int q = 0; q < 8; ++q){
      int   sq = __shfl(s, q, 32);
      float vq = __shfl(v, q, 32);
      float4 xv = x4[(size_t)sq*32 + lane];
      acc.x = fmaf(vq, xv.x, acc.x);
      acc.y = fmaf(vq, xv.y, acc.y);
      acc.z = fmaf(vq, xv.z, acc.z);
      acc.w = fmaf(vq, xv.w, acc.w);
    }
  }
  size_t ii = (size_t)node*32 + lane;
  float dgn = dg[node];
  float4 xi = x4[ii];
  float4 r;
  r.x = alpha*(acc.x + dgn*xi.x);
  r.y = alpha*(acc.y + dgn*xi.y);
  r.z = alpha*(acc.z + dgn*xi.z);
  r.w = alpha*(acc.w + dgn*xi.w);
  if (z){
    float4 zi = ((const float4*)z)[ii];
    r.x = fmaf(beta, zi.x, r.x);
    r.y = fmaf(beta, zi.y, r.y);
    r.z = fmaf(beta, zi.z, r.z);
    r.w = fmaf(beta, zi.w, r.w);
  }
  ((float4*)y)[ii] = r;
}

// F=32 floats/node: 8-lane group per node, float4 per lane, unroll x8.
__global__ __launch_bounds__(256) void spmm32_kernel(
    const int* __restrict__ ptrv, const int* __restrict__ srcs, const float* __restrict__ vals,
    const float* __restrict__ dg, const float* __restrict__ x, const float* __restrict__ z,
    float* __restrict__ y, int N, float alpha, float beta){
  int t = threadIdx.x;
  int g = t >> 3, lane = t & 7;
  int node = blockIdx.x*32 + g;
  if (node >= N) return;
  int e0 = ptrv[node], e1 = ptrv[node+1];
  const float4* x4 = (const float4*)x;
  float4 acc = make_float4(0.f,0.f,0.f,0.f);
  for (int eb = e0; eb < e1; eb += 8){
    int j = eb + lane;
    int s = srcs[j]; float v = vals[j];
    #pragma unroll
    for (int q = 0; q < 8; ++q){
      int   sq = __shfl(s, q, 8);
      float vq = __shfl(v, q, 8);
      float4 xv = x4[(size_t)sq*8 + lane];
      acc.x = fmaf(vq, xv.x, acc.x);
      acc.y = fmaf(vq, xv.y, acc.y);
      acc.z = fmaf(vq, xv.z, acc.z);
      acc.w = fmaf(vq, xv.w, acc.w);
    }
  }
  size_t ii = (size_t)node*8 + lane;
  float dgn = dg[node];
  float4 xi = x4[ii];
  float4 r;
  r.x = alpha*(acc.x + dgn*xi.x);
  r.y = alpha*(acc.y + dgn*xi.y);
  r.z = alpha*(acc.z + dgn*xi.z);
  r.w = alpha*(acc.w + dgn*xi.w);
  if (z){
    float4 zi = ((const float4*)z)[ii];
    r.x = fmaf(beta, zi.x, r.x);
    r.y = fmaf(beta, zi.y, r.y);
    r.z = fmaf(beta, zi.z, r.z);
    r.w = fmaf(beta, zi.w, r.w);
  }
  ((float4*)y)[ii] = r;
}

// ---------------- fused: th2 = 2*(L HRb) - HRb  +  gateB GRU update ---------
// Pass-2 of the HR basis. x = th1 (gathered), z = HRb. At the epilogue each
// lane holds p0=HRb (zi), p1=th1 (xi), p2=th2 (computed) -> stage in LDS,
// barrier, then each lane computes gh for its 4 output cols and updates H.
__global__ __launch_bounds__(256) void spmm_gateB_kernel(
    const int* __restrict__ ptrv, const int* __restrict__ srcs, const float* __restrict__ vals,
    const float* __restrict__ dg, const float* __restrict__ th1, const float* __restrict__ HRb,
    const float* __restrict__ Whh, const float* __restrict__ bhh,
    const float* __restrict__ Zb, const float* __restrict__ gx2b,
    float* __restrict__ H, int N){
  __shared__ float sp[8][3][128];
  int t = threadIdx.x;
  int g = t >> 5, lane = t & 31;
  int node = blockIdx.x*8 + g;
  bool valid = (node < N);
  if (!valid) node = N-1;
  size_t ii = (size_t)node*32 + lane;
  const float4* x4 = (const float4*)th1;
  const float4* z4 = (const float4*)HRb;
  // prefetch epilogue operands early (independent of gather loop)
  float4 Zv   = ((const float4*)Zb)[ii];
  float4 Gx   = ((const float4*)gx2b)[ii];
  float4 Hold = ((const float4*)H)[ii];
  float4 zi   = z4[ii];
  int e0 = ptrv[node], e1 = ptrv[node+1];
  float4 acc = make_float4(0.f,0.f,0.f,0.f);
  for (int eb = e0; eb < e1; eb += 8){
    int j = eb + (lane & 7);
    int s = srcs[j]; float v = vals[j];
    #pragma unroll
    for (int q = 0; q < 8; ++q){
      int   sq = __shfl(s, q, 32);
      float vq = __shfl(v, q, 32);
      float4 xv = x4[(size_t)sq*32 + lane];
      acc.x = fmaf(vq, xv.x, acc.x);
      acc.y = fmaf(vq, xv.y, acc.y);
      acc.z = fmaf(vq, xv.z, acc.z);
      acc.w = fmaf(vq, xv.w, acc.w);
    }
  }
  float dgn = dg[node];
  float4 xi = x4[ii];
  float4 p2;
  p2.x = 2.f*(acc.x + dgn*xi.x) - zi.x;
  p2.y = 2.f*(acc.y + dgn*xi.y) - zi.y;
  p2.z = 2.f*(acc.z + dgn*xi.z) - zi.z;
  p2.w = 2.f*(acc.w + dgn*xi.w) - zi.w;
  // stage p0,p1,p2 for this node's 128 floats
  ((float4*)&sp[g][0][0])[lane] = zi;   // T0 = HRb
  ((float4*)&sp[g][1][0])[lane] = xi;   // T1 = th1
  ((float4*)&sp[g][2][0])[lane] = p2;   // T2
  __syncthreads();
  // gateB: cols f = 4*lane..4*lane+3; b = lane>>3, h = 4*(lane&7)+c
  int b = lane >> 3;
  int h0c = (lane & 7) * 4;
  const float4* W4 = (const float4*)Whh;
  float4 bb = ((const float4*)bhh)[lane & 7];
  float gh0 = bb.x, gh1 = bb.y, gh2 = bb.z, gh3 = bb.w;
  #pragma unroll 1
  for (int k = 0; k < 3; ++k){
    const float* pk = &sp[g][k][b*32];
    #pragma unroll
    for (int o = 0; o < 32; o += 4){
      float4 pv = *reinterpret_cast<const float4*>(pk + o);
      #pragma unroll
      for (int oo = 0; oo < 4; ++oo){
        float p = reinterpret_cast<const float*>(&pv)[oo];
        float4 wv = W4[k*256 + (o+oo)*8 + (lane & 7)];
        gh0 = fmaf(p, wv.x, gh0);
        gh1 = fmaf(p, wv.y, gh1);
        gh2 = fmaf(p, wv.z, gh2);
        gh3 = fmaf(p, wv.w, gh3);
      }
    }
  }
  if (valid){
    float4 Hn;
    float Ht;
    Ht = tanhf(Gx.x + gh0); Hn.x = Zv.x*Hold.x + (1.f - Zv.x)*Ht;
    Ht = tanhf(Gx.y + gh1); Hn.y = Zv.y*Hold.y + (1.f - Zv.y)*Ht;
    Ht = tanhf(Gx.z + gh2); Hn.z = Zv.z*Hold.z + (1.f - Zv.z)*Ht;
    Ht = tanhf(Gx.w + gh3); Hn.w = Zv.w*Hold.w + (1.f - Zv.w)*Ht;
    ((float4*)H)[ii] = Hn;
  }
}

// ---------------- transpose layer-0 input: [B,T,N,8] -> [N, B*8] for step t ----
__global__ void transpose_x_kernel(const float* __restrict__ in, float* __restrict__ out,
                                   int N, int t){
  int idx = blockIdx.x*blockDim.x + threadIdx.x;   // over N*32
  if (idx >= N*32) return;
  int n = idx >> 5; int r = idx & 31; int b = r >> 3; int i = r & 7;
  out[idx] = in[(((size_t)b*12 + t)*N + n)*8 + i];
}

// ---------------- gate A (register-tiled GEMM, R4) ----------------
template<int FIN>
__global__ __launch_bounds__(256) void gateA_kernel(
    const float* __restrict__ x0, const float* __restrict__ x1, const float* __restrict__ x2,
    const float* __restrict__ h0, const float* __restrict__ h1, const float* __restrict__ h2,
    const float* __restrict__ Wx, const float* __restrict__ bx,
    const float* __restrict__ Wh, const float* __restrict__ bh,
    float* __restrict__ Zb, float* __restrict__ gx2b, float* __restrict__ HRb, int M){
  int t = threadIdx.x;
  int h = t & 31, ty = t >> 5;
  int row0 = blockIdx.x*64 + ty*8;
  if (row0 >= M) return;
  bool full = (row0 + 8 <= M);

  float ag0[8]={0,0,0,0,0,0,0,0}, ag1[8]={0,0,0,0,0,0,0,0}, ag2[8]={0,0,0,0,0,0,0,0};
  float az[8]={0,0,0,0,0,0,0,0}, ar[8]={0,0,0,0,0,0,0,0};

  const float* xm[3] = {x0, x1, x2};
  const float* hm[3] = {h0, h1, h2};
  const int gstride = 3*FIN*32;

  #pragma unroll 1
  for (int k3 = 0; k3 < 3; ++k3){
    const float* Ak = xm[k3];
    const float* wb = Wx + k3*FIN*32 + h;
    #pragma unroll 1
    for (int k = 0; k < FIN; k += 4){
      float4 a4[8];
      #pragma unroll
      for (int r = 0; r < 8; ++r){
        int rr = row0 + r; if (!full && rr >= M) rr = M-1;
        a4[r] = *reinterpret_cast<const float4*>(Ak + (size_t)rr*FIN + k);
      }
      #pragma unroll
      for (int kk = 0; kk < 4; ++kk){
        float w0 = wb[(k+kk)*32];
        float w1 = wb[(size_t)gstride   + (k+kk)*32];
        float w2 = wb[(size_t)gstride*2 + (k+kk)*32];
        #pragma unroll
        for (int r = 0; r < 8; ++r){
          float av = reinterpret_cast<const float*>(&a4[r])[kk];
          ag0[r] = fmaf(av, w0, ag0[r]);
          ag1[r] = fmaf(av, w1, ag1[r]);
          ag2[r] = fmaf(av, w2, ag2[r]);
        }
      }
    }
  }

  #pragma unroll 1
  for (int k3 = 0; k3 < 3; ++k3){
    const float* Ak = hm[k3];
    const float* wbz = Wh + k3*1024 + h;          // Wh[0][k3][o][h]
    #pragma unroll 1
    for (int k = 0; k < 32; k += 4){
      float4 a4[8];
      #pragma unroll
      for (int r = 0; r < 8; ++r){
        int rr = row0 + r; if (!full && rr >= M) rr = M-1;
        a4[r] = *reinterpret_cast<const float4*>(Ak + (size_t)rr*32 + k);
      }
      #pragma unroll
      for (int kk = 0; kk < 4; ++kk){
        float wz = wbz[(k+kk)*32];
        float wr = wbz[3072 + (k+kk)*32];
        #pragma unroll
        for (int r = 0; r < 8; ++r){
          float av = reinterpret_cast<const float*>(&a4[r])[kk];
          az[r] = fmaf(av, wz, az[r]);
          ar[r] = fmaf(av, wr, ar[r]);
        }
      }
    }
  }

  float b0 = bx[h], b1 = bx[32+h], b2 = bx[64+h];
  float bz = bh[h], br = bh[32+h];
  #pragma unroll
  for (int r = 0; r < 8; ++r){
    int rr = row0 + r; if (rr >= M) break;
    float Z = sigmoidf_(ag0[r] + b0 + az[r] + bz);
    float R = sigmoidf_(ag1[r] + b1 + ar[r] + br);
    size_t ix = (size_t)rr*32 + h;
    Zb[ix]   = Z;
    gx2b[ix] = ag2[r] + b2;
    HRb[ix]  = h0[ix] * R;
  }
}

// ---------------- readout ----------------
__global__ void readout_kernel(const float* __restrict__ H1, const float* __restrict__ muW,
                               const float* __restrict__ mub, const float* __restrict__ sgW,
                               const float* __restrict__ sgb, float* __restrict__ outp, int N){
  int idx = blockIdx.x*blockDim.x + threadIdx.x;   // over 4*N
  if (idx >= 4*N) return;
  int b = idx / N, n = idx - b*N;
  const float* h = H1 + (size_t)n*128 + b*32;
  float m0 = mub[0], m1 = mub[1], s0 = sgb[0], s1 = sgb[1];
  #pragma unroll
  for (int o = 0; o < 32; ++o){
    float v = h[o];
    m0 = fmaf(v, muW[o*2+0], m0);
    m1 = fmaf(v, muW[o*2+1], m1);
    s0 = fmaf(v, sgW[o*2+0], s0);
    s1 = fmaf(v, sgW[o*2+1], s1);
  }
  size_t base = (size_t)(b*N + n)*2;
  outp[base]   = sigmoidf_(m0);
  outp[base+1] = sigmoidf_(m1);
  size_t sb = (size_t)8*N + base;
  outp[sb]   = (s0 > 15.f) ? s0 : log1pf(__expf(s0));
  outp[sb+1] = (s1 > 15.f) ? s1 : log1pf(__expf(s1));
}

__global__ void mean_kernel(const float* __restrict__ H1, float* __restrict__ mixsum, int N){
  int t = threadIdx.x;   // 128 = (b,o)
  int chunk = (N + gridDim.x - 1) / gridDim.x;
  int n0 = blockIdx.x*chunk, n1 = min(N, n0 + chunk);
  float acc = 0.f;
  for (int n = n0; n < n1; ++n) acc += H1[(size_t)n*128 + t];
  atomicAdd(mixsum + t, acc);
}

__global__ void softmax_kernel(const float* __restrict__ mixsum, float* __restrict__ outp,
                               float invN){
  __shared__ float v[128];
  __shared__ float e[128];
  int t = threadIdx.x; int b = t >> 5;
  float m = mixsum[t]*invN;
  v[t] = m; __syncthreads();
  float mx = -1e30f;
  for (int o = 0; o < 32; ++o) mx = fmaxf(mx, v[b*32 + o]);
  float ex = __expf(m - mx);
  e[t] = ex; __syncthreads();
  float s = 0.f;
  for (int o = 0; o < 32; ++o) s += e[b*32 + o];
  outp[t] = ex / s;
}

// ---------------------------------------------------------------------------

extern "C" void kernel_launch(void* const* d_in, const int* in_sizes, int n_in,
                              void* d_out, int out_size, void* d_ws, size_t ws_size,
                              hipStream_t stream){
  const float* in0  = (const float*)d_in[0];
  const void*  eidx = d_in[1];
  const float* ew   = (const float*)d_in[2];
  const float* Wx0  = (const float*)d_in[3];
  const float* Wh0  = (const float*)d_in[4];
  const float* bx0  = (const float*)d_in[5];
  const float* bh0  = (const float*)d_in[6];
  const float* Wx1  = (const float*)d_in[7];
  const float* Wh1  = (const float*)d_in[8];
  const float* bx1  = (const float*)d_in[9];
  const float* bh1  = (const float*)d_in[10];
  const float* muW  = (const float*)d_in[11];
  const float* mub  = (const float*)d_in[12];
  const float* sgW  = (const float*)d_in[13];
  const float* sgb  = (const float*)d_in[14];
  float* outp = (float*)d_out;

  const int N = in_sizes[0] / (4*12*8);
  const int E = in_sizes[1] / 2;
  const int M = 4*N;
  const int EP = E + 8*N;        // padded-edge capacity

  // ---- carve workspace ----
  char* w = (char*)d_ws;
  size_t off = 0;
  auto alloc = [&](size_t bytes)->void*{
    void* p = w + off;
    off += (bytes + 255) & ~(size_t)255;
    return p;
  };
  int*   row32   = (int*)  alloc((size_t)E*4);
  int*   col32   = (int*)  alloc((size_t)E*4);
  int*   csr_src = (int*)  alloc((size_t)EP*4);
  float* csr_val = (float*)alloc((size_t)EP*4);
  int*   ptrv    = (int*)  alloc((size_t)(N+1)*4);
  int*   cnt     = (int*)  alloc((size_t)N*4);
  int*   cnt2    = (int*)  alloc((size_t)N*4);
  float* deg     = (float*)alloc((size_t)N*4);
  float* dinv    = (float*)alloc((size_t)N*4);
  float* dgv     = (float*)alloc((size_t)N*4);
  int*   flag    = (int*)  alloc(256);
  float* mixsum  = (float*)alloc(512);
  float* xb0     = (float*)alloc((size_t)N*32*4);
  float* xb1     = (float*)alloc((size_t)N*128*4);
  float* xb2     = (float*)alloc((size_t)N*128*4);
  float* th1     = (float*)alloc((size_t)N*128*4);
  float* th2     = (float*)alloc((size_t)N*128*4);
  float* Zb      = (float*)alloc((size_t)N*128*4);
  float* gx2b    = (float*)alloc((size_t)N*128*4);
  float* HRb     = (float*)alloc((size_t)N*128*4);
  float* H0      = (float*)alloc((size_t)N*128*4);
  float* H1      = (float*)alloc((size_t)N*128*4);

  // ---- zero-init (ws is poisoned 0xAA before each call) ----
  hipMemsetAsync(flag,   0, 4, stream);
  hipMemsetAsync(deg,    0, (size_t)N*4, stream);
  hipMemsetAsync(cnt,    0, (size_t)N*4, stream);
  hipMemsetAsync(cnt2,   0, (size_t)N*4, stream);
  hipMemsetAsync(H0,     0, (size_t)N*128*4, stream);
  hipMemsetAsync(H1,     0, (size_t)N*128*4, stream);
  hipMemsetAsync(mixsum, 0, 512, stream);

  // ---- preprocessing: dtype detect, degrees, padded CSR build ----
  {
    int ndw = 4096;
    if (ndw > 2*E) ndw = 2*E;
    int nthread = ndw/2 + 1;
    detect_kernel<<<(nthread+255)/256, 256, 0, stream>>>((const unsigned*)eidx, ndw, flag);
  }
  convert_kernel<<<(E+255)/256, 256, 0, stream>>>(eidx, ew, E, flag, row32, col32, deg, cnt);
  node_prep_kernel<<<(N+255)/256, 256, 0, stream>>>(deg, dinv, dgv, N);
  scan_kernel<<<1, 1024, 0, stream>>>(cnt, ptrv, N);
  fill_kernel<<<(E+255)/256, 256, 0, stream>>>(row32, col32, ew, dinv, ptrv, cnt2,
                                               csr_src, csr_val, E);
  pad_kernel<<<(N+255)/256, 256, 0, stream>>>(cnt, ptrv, csr_src, csr_val, N);

  const int g128 = (N+7)/8;    // spmm128 / fused: 8 nodes / 256 threads
  const int g32  = (N+31)/32;  // spmm32: 32 nodes / 256 threads
  const int gG   = (M+63)/64;  // gateA: 64 rows / 256 threads

  for (int t = 0; t < 12; ++t){
    // ================= layer 0 (Fin=8) =================
    transpose_x_kernel<<<(N*32+255)/256, 256, 0, stream>>>(in0, xb0, N, t);
    spmm32_kernel<<<g32,256,0,stream>>>(ptrv,csr_src,csr_val,dgv, xb0,nullptr,xb1, N, 1.f, 0.f);
    spmm32_kernel<<<g32,256,0,stream>>>(ptrv,csr_src,csr_val,dgv, xb1,xb0,   xb2, N, 2.f,-1.f);
    spmm128_kernel<<<g128,256,0,stream>>>(ptrv,csr_src,csr_val,dgv, H0,nullptr,th1, N, 1.f, 0.f);
    spmm128_kernel<<<g128,256,0,stream>>>(ptrv,csr_src,csr_val,dgv, th1,H0,   th2, N, 2.f,-1.f);
    gateA_kernel<8><<<gG,256,0,stream>>>(xb0,xb1,xb2, H0,th1,th2,
                                         Wx0,bx0, Wh0,bh0, Zb,gx2b,HRb, M);
    spmm128_kernel<<<g128,256,0,stream>>>(ptrv,csr_src,csr_val,dgv, HRb,nullptr,th1, N, 1.f, 0.f);
    spmm_gateB_kernel<<<g128,256,0,stream>>>(ptrv,csr_src,csr_val,dgv, th1,HRb,
                                             Wh0+6144, bh0+64, Zb,gx2b, H0, N);

    // ================= layer 1 (Fin=32, input = H0) =================
    spmm128_kernel<<<g128,256,0,stream>>>(ptrv,csr_src,csr_val,dgv, H0,nullptr,xb1, N, 1.f, 0.f);
    spmm128_kernel<<<g128,256,0,stream>>>(ptrv,csr_src,csr_val,dgv, xb1,H0,   xb2, N, 2.f,-1.f);
    spmm128_kernel<<<g128,256,0,stream>>>(ptrv,csr_src,csr_val,dgv, H1,nullptr,th1, N, 1.f, 0.f);
    spmm128_kernel<<<g128,256,0,stream>>>(ptrv,csr_src,csr_val,dgv, th1,H1,   th2, N, 2.f,-1.f);
    gateA_kernel<32><<<gG,256,0,stream>>>(H0,xb1,xb2, H1,th1,th2,
                                          Wx1,bx1, Wh1,bh1, Zb,gx2b,HRb, M);
    spmm128_kernel<<<g128,256,0,stream>>>(ptrv,csr_src,csr_val,dgv, HRb,nullptr,th1, N, 1.f, 0.f);
    spmm_gateB_kernel<<<g128,256,0,stream>>>(ptrv,csr_src,csr_val,dgv, th1,HRb,
                                             Wh1+6144, bh1+64, Zb,gx2b, H1, N);
  }

  // ---- readout ----
  readout_kernel<<<(4*N+255)/256, 256, 0, stream>>>(H1, muW, mub, sgW, sgb, outp, N);
  mean_kernel<<<256, 128, 0, stream>>>(H1, mixsum, N);
  softmax_kernel<<<1, 128, 0, stream>>>(mixsum, outp + (size_t)16*N, 1.0f/(float)N);
}

// Round 6
// 14716.957 us; speedup vs baseline: 6.3343x; 1.0073x over previous
//
#include <hip/hip_runtime.h>
#include <cstdint>
#include <cstddef>

// ---------------------------------------------------------------------------
// GConvGRU (ChebConv K=3, 2 layers) + readout, for MI355X.
// R6: gateA weights staged in LDS per-k3 panel (R5 profile: weight working set
//     60KB > 32KB L1, act stream evicts it -> dependent L2-latency loads every
//     iter, VALUBusy 41%). Acts double-buffered (mov-free A/B). Fused
//     spmm_gateB also gets LDS-staged Whh. SpMM/padding unchanged from R5.
// ---------------------------------------------------------------------------

__device__ __forceinline__ float sigmoidf_(float x){ return 1.f/(1.f+__expf(-x)); }

// ---------------- preprocessing ----------------

// If edge_index is int64, every odd dword (high word) of the buffer is 0
// (all indices < 50000). If int32, odd dwords are real indices (~0 prob all 0).
__global__ void detect_kernel(const unsigned* __restrict__ buf, int ndw, int* flag){
  int i = blockIdx.x*blockDim.x + threadIdx.x;
  int j = 2*i + 1;
  if (j < ndw && buf[j] != 0u) atomicOr(flag, 1);   // flag=1 -> int32
}

__global__ void convert_kernel(const void* __restrict__ eidx, const float* __restrict__ w,
                               int E, const int* __restrict__ flag,
                               int* __restrict__ row32, int* __restrict__ col32,
                               float* __restrict__ deg, int* __restrict__ cnt){
  int e = blockIdx.x*blockDim.x + threadIdx.x;
  if (e >= E) return;
  int r, c;
  if (*flag){ const int* p = (const int*)eidx; r = p[e]; c = p[E+e]; }
  else { const long long* p = (const long long*)eidx; r = (int)p[e]; c = (int)p[(size_t)E+e]; }
  row32[e] = r; col32[e] = c;
  atomicAdd(deg + r, w[e]);
  atomicAdd(cnt + c, 1);
}

__global__ void node_prep_kernel(const float* __restrict__ deg, float* __restrict__ dinv,
                                 float* __restrict__ dg, int N){
  int n = blockIdx.x*blockDim.x + threadIdx.x;
  if (n >= N) return;
  float d = deg[n];
  if (d > 0.f){ dinv[n] = rsqrtf(d); dg[n] = 0.f; }
  else        { dinv[n] = 0.f;       dg[n] = -1.f; }
}

// Exclusive scan of PADDED counts ((cnt+7)&~7) -> ptr[N+1]. 1 block, 1024 thr.
__global__ void scan_kernel(const int* __restrict__ cnt, int* __restrict__ ptrout, int N){
  __shared__ int s[1024];
  int t = threadIdx.x;
  int chunk = (N + 1023) / 1024;
  int a0 = t*chunk, a1 = min(N, a0 + chunk);
  int sum = 0;
  for (int i = a0; i < a1; ++i) sum += (cnt[i]+7)&~7;
  s[t] = sum; __syncthreads();
  for (int off = 1; off < 1024; off <<= 1){
    int v = (t >= off) ? s[t-off] : 0;
    __syncthreads();
    s[t] += v;
    __syncthreads();
  }
  int run = (t == 0) ? 0 : s[t-1];
  for (int i = a0; i < a1; ++i){ ptrout[i] = run; run += (cnt[i]+7)&~7; }
  if (t == 1023) ptrout[N] = s[1023];
}

__global__ void fill_kernel(const int* __restrict__ row32, const int* __restrict__ col32,
                            const float* __restrict__ w, const float* __restrict__ dinv,
                            const int* __restrict__ ptrv, int* __restrict__ cnt2,
                            int* __restrict__ srcs, float* __restrict__ vals, int E){
  int e = blockIdx.x*blockDim.x + threadIdx.x;
  if (e >= E) return;
  int r = row32[e], c = col32[e];
  int p = ptrv[c] + atomicAdd(cnt2 + c, 1);
  srcs[p] = r;
  vals[p] = -w[e] * dinv[r] * dinv[c];
}

// Fill pad slots [cnt[n], ptr[n+1]-ptr[n]) with (src=n, val=0).
__global__ void pad_kernel(const int* __restrict__ cnt, const int* __restrict__ ptrv,
                           int* __restrict__ srcs, float* __restrict__ vals, int N){
  int n = blockIdx.x*blockDim.x + threadIdx.x;
  if (n >= N) return;
  int base = ptrv[n];
  int real = cnt[n];
  int padded = ptrv[n+1] - base;
  for (int j = real; j < padded; ++j){ srcs[base+j] = n; vals[base+j] = 0.f; }
}

// ---------------- SpMM: y = alpha*(A x + diag*x) + beta*z ----------------
// F=128 floats/node: one 32-lane group per node, float4 per lane (512B row).
// Edge count per node is a multiple of 8 -> inner loop unrolled x8.
__global__ __launch_bounds__(256) void spmm128_kernel(
    const int* __restrict__ ptrv, const int* __restrict__ srcs, const float* __restrict__ vals,
    const float* __restrict__ dg, const float* __restrict__ x, const float* __restrict__ z,
    float* __restrict__ y, int N, float alpha, float beta){
  int t = threadIdx.x;
  int g = t >> 5, lane = t & 31;
  int node = blockIdx.x*8 + g;
  if (node >= N) return;
  int e0 = ptrv[node], e1 = ptrv[node+1];
  const float4* x4 = (const float4*)x;
  float4 acc = make_float4(0.f,0.f,0.f,0.f);
  for (int eb = e0; eb < e1; eb += 8){
    int j = eb + (lane & 7);
    int s = srcs[j]; float v = vals[j];
    #pragma unroll
    for (int q = 0; q < 8; ++q){
      int   sq = __shfl(s, q, 32);
      float vq = __shfl(v, q, 32);
      float4 xv = x4[(size_t)sq*32 + lane];
      acc.x = fmaf(vq, xv.x, acc.x);
      acc.y = fmaf(vq, xv.y, acc.y);
      acc.z = fmaf(vq, xv.z, acc.z);
      acc.w = fmaf(vq, xv.w, acc.w);
    }
  }
  size_t ii = (size_t)node*32 + lane;
  float dgn = dg[node];
  float4 xi = x4[ii];
  float4 r;
  r.x = alpha*(acc.x + dgn*xi.x);
  r.y = alpha*(acc.y + dgn*xi.y);
  r.z = alpha*(acc.z + dgn*xi.z);
  r.w = alpha*(acc.w + dgn*xi.w);
  if (z){
    float4 zi = ((const float4*)z)[ii];
    r.x = fmaf(beta, zi.x, r.x);
    r.y = fmaf(beta, zi.y, r.y);
    r.z = fmaf(beta, zi.z, r.z);
    r.w = fmaf(beta, zi.w, r.w);
  }
  ((float4*)y)[ii] = r;
}

// F=32 floats/node: 8-lane group per node, float4 per lane, unroll x8.
__global__ __launch_bounds__(256) void spmm32_kernel(
    const int* __restrict__ ptrv, const int* __restrict__ srcs, const float* __restrict__ vals,
    const float* __restrict__ dg, const float* __restrict__ x, const float* __restrict__ z,
    float* __restrict__ y, int N, float alpha, float beta){
  int t = threadIdx.x;
  int g = t >> 3, lane = t & 7;
  int node = blockIdx.x*32 + g;
  if (node >= N) return;
  int e0 = ptrv[node], e1 = ptrv[node+1];
  const float4* x4 = (const float4*)x;
  float4 acc = make_float4(0.f,0.f,0.f,0.f);
  for (int eb = e0; eb < e1; eb += 8){
    int j = eb + lane;
    int s = srcs[j]; float v = vals[j];
    #pragma unroll
    for (int q = 0; q < 8; ++q){
      int   sq = __shfl(s, q, 8);
      float vq = __shfl(v, q, 8);
      float4 xv = x4[(size_t)sq*8 + lane];
      acc.x = fmaf(vq, xv.x, acc.x);
      acc.y = fmaf(vq, xv.y, acc.y);
      acc.z = fmaf(vq, xv.z, acc.z);
      acc.w = fmaf(vq, xv.w, acc.w);
    }
  }
  size_t ii = (size_t)node*8 + lane;
  float dgn = dg[node];
  float4 xi = x4[ii];
  float4 r;
  r.x = alpha*(acc.x + dgn*xi.x);
  r.y = alpha*(acc.y + dgn*xi.y);
  r.z = alpha*(acc.z + dgn*xi.z);
  r.w = alpha*(acc.w + dgn*xi.w);
  if (z){
    float4 zi = ((const float4*)z)[ii];
    r.x = fmaf(beta, zi.x, r.x);
    r.y = fmaf(beta, zi.y, r.y);
    r.z = fmaf(beta, zi.z, r.z);
    r.w = fmaf(beta, zi.w, r.w);
  }
  ((float4*)y)[ii] = r;
}

// ---------------- fused: th2 = 2*(L HRb) - HRb  +  gateB GRU update ---------
// Pass-2 of the HR basis. Whh staged in LDS (12KB) concurrently with gather;
// the pre-epilogue barrier covers the staging.
__global__ __launch_bounds__(256) void spmm_gateB_kernel(
    const int* __restrict__ ptrv, const int* __restrict__ srcs, const float* __restrict__ vals,
    const float* __restrict__ dg, const float* __restrict__ th1, const float* __restrict__ HRb,
    const float* __restrict__ Whh, const float* __restrict__ bhh,
    const float* __restrict__ Zb, const float* __restrict__ gx2b,
    float* __restrict__ H, int N){
  __shared__ float sp[8][3][128];
  __shared__ float sW[3072];
  int t = threadIdx.x;
  int g = t >> 5, lane = t & 31;
  int node = blockIdx.x*8 + g;
  bool valid = (node < N);
  if (!valid) node = N-1;
  // stage Whh -> LDS (coalesced); consumed after the barrier below
  for (int idx = t; idx < 3072; idx += 256) sW[idx] = Whh[idx];
  size_t ii = (size_t)node*32 + lane;
  const float4* x4 = (const float4*)th1;
  const float4* z4 = (const float4*)HRb;
  float4 Zv   = ((const float4*)Zb)[ii];
  float4 Gx   = ((const float4*)gx2b)[ii];
  float4 Hold = ((const float4*)H)[ii];
  float4 zi   = z4[ii];
  int e0 = ptrv[node], e1 = ptrv[node+1];
  float4 acc = make_float4(0.f,0.f,0.f,0.f);
  for (int eb = e0; eb < e1; eb += 8){
    int j = eb + (lane & 7);
    int s = srcs[j]; float v = vals[j];
    #pragma unroll
    for (int q = 0; q < 8; ++q){
      int   sq = __shfl(s, q, 32);
      float vq = __shfl(v, q, 32);
      float4 xv = x4[(size_t)sq*32 + lane];
      acc.x = fmaf(vq, xv.x, acc.x);
      acc.y = fmaf(vq, xv.y, acc.y);
      acc.z = fmaf(vq, xv.z, acc.z);
      acc.w = fmaf(vq, xv.w, acc.w);
    }
  }
  float dgn = dg[node];
  float4 xi = x4[ii];
  float4 p2;
  p2.x = 2.f*(acc.x + dgn*xi.x) - zi.x;
  p2.y = 2.f*(acc.y + dgn*xi.y) - zi.y;
  p2.z = 2.f*(acc.z + dgn*xi.z) - zi.z;
  p2.w = 2.f*(acc.w + dgn*xi.w) - zi.w;
  ((float4*)&sp[g][0][0])[lane] = zi;   // T0 = HRb
  ((float4*)&sp[g][1][0])[lane] = xi;   // T1 = th1
  ((float4*)&sp[g][2][0])[lane] = p2;   // T2
  __syncthreads();
  // gateB: cols h = 4*(lane&7)..+3 for batch b = lane>>3
  int b = lane >> 3;
  const float4* W4 = (const float4*)sW;
  float4 bb = ((const float4*)bhh)[lane & 7];
  float gh0 = bb.x, gh1 = bb.y, gh2 = bb.z, gh3 = bb.w;
  #pragma unroll 1
  for (int k = 0; k < 3; ++k){
    const float* pk = &sp[g][k][b*32];
    #pragma unroll
    for (int o = 0; o < 32; o += 4){
      float4 pv = *reinterpret_cast<const float4*>(pk + o);
      #pragma unroll
      for (int oo = 0; oo < 4; ++oo){
        float p = reinterpret_cast<const float*>(&pv)[oo];
        float4 wv = W4[k*256 + (o+oo)*8 + (lane & 7)];
        gh0 = fmaf(p, wv.x, gh0);
        gh1 = fmaf(p, wv.y, gh1);
        gh2 = fmaf(p, wv.z, gh2);
        gh3 = fmaf(p, wv.w, gh3);
      }
    }
  }
  if (valid){
    float4 Hn;
    float Ht;
    Ht = tanhf(Gx.x + gh0); Hn.x = Zv.x*Hold.x + (1.f - Zv.x)*Ht;
    Ht = tanhf(Gx.y + gh1); Hn.y = Zv.y*Hold.y + (1.f - Zv.y)*Ht;
    Ht = tanhf(Gx.z + gh2); Hn.z = Zv.z*Hold.z + (1.f - Zv.z)*Ht;
    Ht = tanhf(Gx.w + gh3); Hn.w = Zv.w*Hold.w + (1.f - Zv.w)*Ht;
    ((float4*)H)[ii] = Hn;
  }
}

// ---------------- transpose layer-0 input: [B,T,N,8] -> [N, B*8] for step t ----
__global__ void transpose_x_kernel(const float* __restrict__ in, float* __restrict__ out,
                                   int N, int t){
  int idx = blockIdx.x*blockDim.x + threadIdx.x;   // over N*32
  if (idx >= N*32) return;
  int n = idx >> 5; int r = idx & 31; int b = r >> 3; int i = r & 7;
  out[idx] = in[(((size_t)b*12 + t)*N + n)*8 + i];
}

// ---------------- gate A: register-tiled GEMM + LDS weight panels ----------
// 64 rows/block (8 ty-groups x 8 rows), 32 h-lanes. Weights staged per-k3
// panel into LDS (broadcast ds_read, conflict-free); acts A/B double-buffered.
// NO early return: all threads reach every barrier (rows clamped, stores
// guarded) — required because M=4N need not be a multiple of 64.
template<int FIN>
__global__ __launch_bounds__(256) void gateA_kernel(
    const float* __restrict__ x0, const float* __restrict__ x1, const float* __restrict__ x2,
    const float* __restrict__ h0, const float* __restrict__ h1, const float* __restrict__ h2,
    const float* __restrict__ Wx, const float* __restrict__ bx,
    const float* __restrict__ Wh, const float* __restrict__ bh,
    float* __restrict__ Zb, float* __restrict__ gx2b, float* __restrict__ HRb, int M){
  int t = threadIdx.x;
  int h = t & 31, ty = t >> 5;
  int row0 = blockIdx.x*64 + ty*8;

  __shared__ float swx[3*FIN*32];   // [gate][i][h] panel for current k3
  __shared__ float swh[2*32*32];    // [gate(z,r)][o][h] panel for current k3

  float ag0[8]={0,0,0,0,0,0,0,0}, ag1[8]={0,0,0,0,0,0,0,0}, ag2[8]={0,0,0,0,0,0,0,0};
  float az[8]={0,0,0,0,0,0,0,0}, ar[8]={0,0,0,0,0,0,0,0};

  int rowc[8];
  #pragma unroll
  for (int r = 0; r < 8; ++r){ int rr = row0 + r; rowc[r] = (rr < M) ? rr : (M-1); }

  const float* xm[3] = {x0, x1, x2};
  const float* hm[3] = {h0, h1, h2};

  // ---- x-part ----
  #pragma unroll 1
  for (int k3 = 0; k3 < 3; ++k3){
    __syncthreads();   // previous panel fully consumed
    for (int idx = t; idx < 3*FIN*32; idx += 256){
      int g = idx / (FIN*32); int rem = idx - g*(FIN*32);
      swx[idx] = Wx[(size_t)g*(3*FIN*32) + k3*(FIN*32) + rem];
    }
    __syncthreads();
    const float* Ak = xm[k3];
    float4 a4a[8], a4b[8];
    #pragma unroll
    for (int r = 0; r < 8; ++r) a4a[r] = *reinterpret_cast<const float4*>(Ak + (size_t)rowc[r]*FIN);
    #pragma unroll 1
    for (int k = 0; k < FIN; k += 8){
      #pragma unroll
      for (int r = 0; r < 8; ++r) a4b[r] = *reinterpret_cast<const float4*>(Ak + (size_t)rowc[r]*FIN + k + 4);
      #pragma unroll
      for (int kk = 0; kk < 4; ++kk){
        float w0 = swx[(0*FIN + k+kk)*32 + h];
        float w1 = swx[(1*FIN + k+kk)*32 + h];
        float w2 = swx[(2*FIN + k+kk)*32 + h];
        #pragma unroll
        for (int r = 0; r < 8; ++r){
          float av = reinterpret_cast<const float*>(&a4a[r])[kk];
          ag0[r] = fmaf(av, w0, ag0[r]);
          ag1[r] = fmaf(av, w1, ag1[r]);
          ag2[r] = fmaf(av, w2, ag2[r]);
        }
      }
      if (k + 8 < FIN){
        #pragma unroll
        for (int r = 0; r < 8; ++r) a4a[r] = *reinterpret_cast<const float4*>(Ak + (size_t)rowc[r]*FIN + k + 8);
      }
      #pragma unroll
      for (int kk = 0; kk < 4; ++kk){
        float w0 = swx[(0*FIN + k+4+kk)*32 + h];
        float w1 = swx[(1*FIN + k+4+kk)*32 + h];
        float w2 = swx[(2*FIN + k+4+kk)*32 + h];
        #pragma unroll
        for (int r = 0; r < 8; ++r){
          float av = reinterpret_cast<const float*>(&a4b[r])[kk];
          ag0[r] = fmaf(av, w0, ag0[r]);
          ag1[r] = fmaf(av, w1, ag1[r]);
          ag2[r] = fmaf(av, w2, ag2[r]);
        }
      }
    }
  }

  // ---- h-part ----
  #pragma unroll 1
  for (int k3 = 0; k3 < 3; ++k3){
    __syncthreads();
    for (int idx = t; idx < 2048; idx += 256){
      int g = idx >> 10; int rem = idx & 1023;
      swh[idx] = Wh[(size_t)g*3072 + k3*1024 + rem];
    }
    __syncthreads();
    const float* Ak = hm[k3];
    float4 a4a[8], a4b[8];
    #pragma unroll
    for (int r = 0; r < 8; ++r) a4a[r] = *reinterpret_cast<const float4*>(Ak + (size_t)rowc[r]*32);
    #pragma unroll 1
    for (int k = 0; k < 32; k += 8){
      #pragma unroll
      for (int r = 0; r < 8; ++r) a4b[r] = *reinterpret_cast<const float4*>(Ak + (size_t)rowc[r]*32 + k + 4);
      #pragma unroll
      for (int kk = 0; kk < 4; ++kk){
        float wz = swh[(k+kk)*32 + h];
        float wr = swh[1024 + (k+kk)*32 + h];
        #pragma unroll
        for (int r = 0; r < 8; ++r){
          float av = reinterpret_cast<const float*>(&a4a[r])[kk];
          az[r] = fmaf(av, wz, az[r]);
          ar[r] = fmaf(av, wr, ar[r]);
        }
      }
      if (k + 8 < 32){
        #pragma unroll
        for (int r = 0; r < 8; ++r) a4a[r] = *reinterpret_cast<const float4*>(Ak + (size_t)rowc[r]*32 + k + 8);
      }
      #pragma unroll
      for (int kk = 0; kk < 4; ++kk){
        float wz = swh[(k+4+kk)*32 + h];
        float wr = swh[1024 + (k+4+kk)*32 + h];
        #pragma unroll
        for (int r = 0; r < 8; ++r){
          float av = reinterpret_cast<const float*>(&a4b[r])[kk];
          az[r] = fmaf(av, wz, az[r]);
          ar[r] = fmaf(av, wr, ar[r]);
        }
      }
    }
  }

  float b0 = bx[h], b1 = bx[32+h], b2 = bx[64+h];
  float bz = bh[h], br = bh[32+h];
  #pragma unroll
  for (int r = 0; r < 8; ++r){
    int rr = row0 + r; if (rr >= M) break;
    float Z = sigmoidf_(ag0[r] + b0 + az[r] + bz);
    float R = sigmoidf_(ag1[r] + b1 + ar[r] + br);
    size_t ix = (size_t)rr*32 + h;
    Zb[ix]   = Z;
    gx2b[ix] = ag2[r] + b2;
    HRb[ix]  = h0[ix] * R;
  }
}

// ---------------- readout ----------------
__global__ void readout_kernel(const float* __restrict__ H1, const float* __restrict__ muW,
                               const float* __restrict__ mub, const float* __restrict__ sgW,
                               const float* __restrict__ sgb, float* __restrict__ outp, int N){
  int idx = blockIdx.x*blockDim.x + threadIdx.x;   // over 4*N
  if (idx >= 4*N) return;
  int b = idx / N, n = idx - b*N;
  const float* h = H1 + (size_t)n*128 + b*32;
  float m0 = mub[0], m1 = mub[1], s0 = sgb[0], s1 = sgb[1];
  #pragma unroll
  for (int o = 0; o < 32; ++o){
    float v = h[o];
    m0 = fmaf(v, muW[o*2+0], m0);
    m1 = fmaf(v, muW[o*2+1], m1);
    s0 = fmaf(v, sgW[o*2+0], s0);
    s1 = fmaf(v, sgW[o*2+1], s1);
  }
  size_t base = (size_t)(b*N + n)*2;
  outp[base]   = sigmoidf_(m0);
  outp[base+1] = sigmoidf_(m1);
  size_t sb = (size_t)8*N + base;
  outp[sb]   = (s0 > 15.f) ? s0 : log1pf(__expf(s0));
  outp[sb+1] = (s1 > 15.f) ? s1 : log1pf(__expf(s1));
}

__global__ void mean_kernel(const float* __restrict__ H1, float* __restrict__ mixsum, int N){
  int t = threadIdx.x;   // 128 = (b,o)
  int chunk = (N + gridDim.x - 1) / gridDim.x;
  int n0 = blockIdx.x*chunk, n1 = min(N, n0 + chunk);
  float acc = 0.f;
  for (int n = n0; n < n1; ++n) acc += H1[(size_t)n*128 + t];
  atomicAdd(mixsum + t, acc);
}

__global__ void softmax_kernel(const float* __restrict__ mixsum, float* __restrict__ outp,
                               float invN){
  __shared__ float v[128];
  __shared__ float e[128];
  int t = threadIdx.x; int b = t >> 5;
  float m = mixsum[t]*invN;
  v[t] = m; __syncthreads();
  float mx = -1e30f;
  for (int o = 0; o < 32; ++o) mx = fmaxf(mx, v[b*32 + o]);
  float ex = __expf(m - mx);
  e[t] = ex; __syncthreads();
  float s = 0.f;
  for (int o = 0; o < 32; ++o) s += e[b*32 + o];
  outp[t] = ex / s;
}

// ---------------------------------------------------------------------------

extern "C" void kernel_launch(void* const* d_in, const int* in_sizes, int n_in,
                              void* d_out, int out_size, void* d_ws, size_t ws_size,
                              hipStream_t stream){
  const float* in0  = (const float*)d_in[0];
  const void*  eidx = d_in[1];
  const float* ew   = (const float*)d_in[2];
  const float* Wx0  = (const float*)d_in[3];
  const float* Wh0  = (const float*)d_in[4];
  const float* bx0  = (const float*)d_in[5];
  const float* bh0  = (const float*)d_in[6];
  const float* Wx1  = (const float*)d_in[7];
  const float* Wh1  = (const float*)d_in[8];
  const float* bx1  = (const float*)d_in[9];
  const float* bh1  = (const float*)d_in[10];
  const float* muW  = (const float*)d_in[11];
  const float* mub  = (const float*)d_in[12];
  const float* sgW  = (const float*)d_in[13];
  const float* sgb  = (const float*)d_in[14];
  float* outp = (float*)d_out;

  const int N = in_sizes[0] / (4*12*8);
  const int E = in_sizes[1] / 2;
  const int M = 4*N;
  const int EP = E + 8*N;        // padded-edge capacity

  // ---- carve workspace ----
  char* w = (char*)d_ws;
  size_t off = 0;
  auto alloc = [&](size_t bytes)->void*{
    void* p = w + off;
    off += (bytes + 255) & ~(size_t)255;
    return p;
  };
  int*   row32   = (int*)  alloc((size_t)E*4);
  int*   col32   = (int*)  alloc((size_t)E*4);
  int*   csr_src = (int*)  alloc((size_t)EP*4);
  float* csr_val = (float*)alloc((size_t)EP*4);
  int*   ptrv    = (int*)  alloc((size_t)(N+1)*4);
  int*   cnt     = (int*)  alloc((size_t)N*4);
  int*   cnt2    = (int*)  alloc((size_t)N*4);
  float* deg     = (float*)alloc((size_t)N*4);
  float* dinv    = (float*)alloc((size_t)N*4);
  float* dgv     = (float*)alloc((size_t)N*4);
  int*   flag    = (int*)  alloc(256);
  float* mixsum  = (float*)alloc(512);
  float* xb0     = (float*)alloc((size_t)N*32*4);
  float* xb1     = (float*)alloc((size_t)N*128*4);
  float* xb2     = (float*)alloc((size_t)N*128*4);
  float* th1     = (float*)alloc((size_t)N*128*4);
  float* th2     = (float*)alloc((size_t)N*128*4);
  float* Zb      = (float*)alloc((size_t)N*128*4);
  float* gx2b    = (float*)alloc((size_t)N*128*4);
  float* HRb     = (float*)alloc((size_t)N*128*4);
  float* H0      = (float*)alloc((size_t)N*128*4);
  float* H1      = (float*)alloc((size_t)N*128*4);

  // ---- zero-init (ws is poisoned 0xAA before each call) ----
  hipMemsetAsync(flag,   0, 4, stream);
  hipMemsetAsync(deg,    0, (size_t)N*4, stream);
  hipMemsetAsync(cnt,    0, (size_t)N*4, stream);
  hipMemsetAsync(cnt2,   0, (size_t)N*4, stream);
  hipMemsetAsync(H0,     0, (size_t)N*128*4, stream);
  hipMemsetAsync(H1,     0, (size_t)N*128*4, stream);
  hipMemsetAsync(mixsum, 0, 512, stream);

  // ---- preprocessing: dtype detect, degrees, padded CSR build ----
  {
    int ndw = 4096;
    if (ndw > 2*E) ndw = 2*E;
    int nthread = ndw/2 + 1;
    detect_kernel<<<(nthread+255)/256, 256, 0, stream>>>((const unsigned*)eidx, ndw, flag);
  }
  convert_kernel<<<(E+255)/256, 256, 0, stream>>>(eidx, ew, E, flag, row32, col32, deg, cnt);
  node_prep_kernel<<<(N+255)/256, 256, 0, stream>>>(deg, dinv, dgv, N);
  scan_kernel<<<1, 1024, 0, stream>>>(cnt, ptrv, N);
  fill_kernel<<<(E+255)/256, 256, 0, stream>>>(row32, col32, ew, dinv, ptrv, cnt2,
                                               csr_src, csr_val, E);
  pad_kernel<<<(N+255)/256, 256, 0, stream>>>(cnt, ptrv, csr_src, csr_val, N);

  const int g128 = (N+7)/8;    // spmm128 / fused: 8 nodes / 256 threads
  const int g32  = (N+31)/32;  // spmm32: 32 nodes / 256 threads
  const int gG   = (M+63)/64;  // gateA: 64 rows / 256 threads

  for (int t = 0; t < 12; ++t){
    // ================= layer 0 (Fin=8) =================
    transpose_x_kernel<<<(N*32+255)/256, 256, 0, stream>>>(in0, xb0, N, t);
    spmm32_kernel<<<g32,256,0,stream>>>(ptrv,csr_src,csr_val,dgv, xb0,nullptr,xb1, N, 1.f, 0.f);
    spmm32_kernel<<<g32,256,0,stream>>>(ptrv,csr_src,csr_val,dgv, xb1,xb0,   xb2, N, 2.f,-1.f);
    spmm128_kernel<<<g128,256,0,stream>>>(ptrv,csr_src,csr_val,dgv, H0,nullptr,th1, N, 1.f, 0.f);
    spmm128_kernel<<<g128,256,0,stream>>>(ptrv,csr_src,csr_val,dgv, th1,H0,   th2, N, 2.f,-1.f);
    gateA_kernel<8><<<gG,256,0,stream>>>(xb0,xb1,xb2, H0,th1,th2,
                                         Wx0,bx0, Wh0,bh0, Zb,gx2b,HRb, M);
    spmm128_kernel<<<g128,256,0,stream>>>(ptrv,csr_src,csr_val,dgv, HRb,nullptr,th1, N, 1.f, 0.f);
    spmm_gateB_kernel<<<g128,256,0,stream>>>(ptrv,csr_src,csr_val,dgv, th1,HRb,
                                             Wh0+6144, bh0+64, Zb,gx2b, H0, N);

    // ================= layer 1 (Fin=32, input = H0) =================
    spmm128_kernel<<<g128,256,0,stream>>>(ptrv,csr_src,csr_val,dgv, H0,nullptr,xb1, N, 1.f, 0.f);
    spmm128_kernel<<<g128,256,0,stream>>>(ptrv,csr_src,csr_val,dgv, xb1,H0,   xb2, N, 2.f,-1.f);
    spmm128_kernel<<<g128,256,0,stream>>>(ptrv,csr_src,csr_val,dgv, H1,nullptr,th1, N, 1.f, 0.f);
    spmm128_kernel<<<g128,256,0,stream>>>(ptrv,csr_src,csr_val,dgv, th1,H1,   th2, N, 2.f,-1.f);
    gateA_kernel<32><<<gG,256,0,stream>>>(H0,xb1,xb2, H1,th1,th2,
                                          Wx1,bx1, Wh1,bh1, Zb,gx2b,HRb, M);
    spmm128_kernel<<<g128,256,0,stream>>>(ptrv,csr_src,csr_val,dgv, HRb,nullptr,th1, N, 1.f, 0.f);
    spmm_gateB_kernel<<<g128,256,0,stream>>>(ptrv,csr_src,csr_val,dgv, th1,HRb,
                                             Wh1+6144, bh1+64, Zb,gx2b, H1, N);
  }

  // ---- readout ----
  readout_kernel<<<(4*N+255)/256, 256, 0, stream>>>(H1, muW, mub, sgW, sgb, outp, N);
  mean_kernel<<<256, 128, 0, stream>>>(H1, mixsum, N);
  softmax_kernel<<<1, 128, 0, stream>>>(mixsum, outp + (size_t)16*N, 1.0f/(float)N);
}

// Round 8
// 12783.070 us; speedup vs baseline: 7.2926x; 1.1513x over previous
//
#include <hip/hip_runtime.h>
#include <cstdint>
#include <cstddef>

// ---------------------------------------------------------------------------
// GConvGRU (ChebConv K=3, 2 layers) + readout, for MI355X.
// R8: conservative bisect after R7's post-timing divergence.
//     Kernel set = R5's gateA (72 VGPR, no LDS panels) + R6's spmm_gateB
//     (LDS-staged Whh) + R5 padded/unrolled spmm — ALL previously passing.
//     Only structural change kept from R7: basis(H0) cache — layer1's x-basis
//     (xb1/xb2) is reused as layer0's h-basis next step; layer0's 2 h-basis
//     spmm128s deleted; t=0 cache = memset 0 (basis(0)=0 exactly).
//     Layer0's 32-wide x-basis lives in th1's dead region (ws stays 257MB).
//     NO aliasing, NO gate split, NO spmm_gateAh (R7 suspects removed).
// ---------------------------------------------------------------------------

__device__ __forceinline__ float sigmoidf_(float x){ return 1.f/(1.f+__expf(-x)); }

// ---------------- preprocessing ----------------

__global__ void detect_kernel(const unsigned* __restrict__ buf, int ndw, int* flag){
  int i = blockIdx.x*blockDim.x + threadIdx.x;
  int j = 2*i + 1;
  if (j < ndw && buf[j] != 0u) atomicOr(flag, 1);   // flag=1 -> int32
}

__global__ void convert_kernel(const void* __restrict__ eidx, const float* __restrict__ w,
                               int E, const int* __restrict__ flag,
                               int* __restrict__ row32, int* __restrict__ col32,
                               float* __restrict__ deg, int* __restrict__ cnt){
  int e = blockIdx.x*blockDim.x + threadIdx.x;
  if (e >= E) return;
  int r, c;
  if (*flag){ const int* p = (const int*)eidx; r = p[e]; c = p[E+e]; }
  else { const long long* p = (const long long*)eidx; r = (int)p[e]; c = (int)p[(size_t)E+e]; }
  row32[e] = r; col32[e] = c;
  atomicAdd(deg + r, w[e]);
  atomicAdd(cnt + c, 1);
}

__global__ void node_prep_kernel(const float* __restrict__ deg, float* __restrict__ dinv,
                                 float* __restrict__ dg, int N){
  int n = blockIdx.x*blockDim.x + threadIdx.x;
  if (n >= N) return;
  float d = deg[n];
  if (d > 0.f){ dinv[n] = rsqrtf(d); dg[n] = 0.f; }
  else        { dinv[n] = 0.f;       dg[n] = -1.f; }
}

// Exclusive scan of PADDED counts ((cnt+7)&~7) -> ptr[N+1]. 1 block, 1024 thr.
__global__ void scan_kernel(const int* __restrict__ cnt, int* __restrict__ ptrout, int N){
  __shared__ int s[1024];
  int t = threadIdx.x;
  int chunk = (N + 1023) / 1024;
  int a0 = t*chunk, a1 = min(N, a0 + chunk);
  int sum = 0;
  for (int i = a0; i < a1; ++i) sum += (cnt[i]+7)&~7;
  s[t] = sum; __syncthreads();
  for (int off = 1; off < 1024; off <<= 1){
    int v = (t >= off) ? s[t-off] : 0;
    __syncthreads();
    s[t] += v;
    __syncthreads();
  }
  int run = (t == 0) ? 0 : s[t-1];
  for (int i = a0; i < a1; ++i){ ptrout[i] = run; run += (cnt[i]+7)&~7; }
  if (t == 1023) ptrout[N] = s[1023];
}

__global__ void fill_kernel(const int* __restrict__ row32, const int* __restrict__ col32,
                            const float* __restrict__ w, const float* __restrict__ dinv,
                            const int* __restrict__ ptrv, int* __restrict__ cnt2,
                            int* __restrict__ srcs, float* __restrict__ vals, int E){
  int e = blockIdx.x*blockDim.x + threadIdx.x;
  if (e >= E) return;
  int r = row32[e], c = col32[e];
  int p = ptrv[c] + atomicAdd(cnt2 + c, 1);
  srcs[p] = r;
  vals[p] = -w[e] * dinv[r] * dinv[c];
}

__global__ void pad_kernel(const int* __restrict__ cnt, const int* __restrict__ ptrv,
                           int* __restrict__ srcs, float* __restrict__ vals, int N){
  int n = blockIdx.x*blockDim.x + threadIdx.x;
  if (n >= N) return;
  int base = ptrv[n];
  int real = cnt[n];
  int padded = ptrv[n+1] - base;
  for (int j = real; j < padded; ++j){ srcs[base+j] = n; vals[base+j] = 0.f; }
}

// ---------------- SpMM: y = alpha*(A x + diag*x) + beta*z ----------------
__global__ __launch_bounds__(256) void spmm128_kernel(
    const int* __restrict__ ptrv, const int* __restrict__ srcs, const float* __restrict__ vals,
    const float* __restrict__ dg, const float* __restrict__ x, const float* __restrict__ z,
    float* __restrict__ y, int N, float alpha, float beta){
  int t = threadIdx.x;
  int g = t >> 5, lane = t & 31;
  int node = blockIdx.x*8 + g;
  if (node >= N) return;
  int e0 = ptrv[node], e1 = ptrv[node+1];
  const float4* x4 = (const float4*)x;
  float4 acc = make_float4(0.f,0.f,0.f,0.f);
  for (int eb = e0; eb < e1; eb += 8){
    int j = eb + (lane & 7);
    int s = srcs[j]; float v = vals[j];
    #pragma unroll
    for (int q = 0; q < 8; ++q){
      int   sq = __shfl(s, q, 32);
      float vq = __shfl(v, q, 32);
      float4 xv = x4[(size_t)sq*32 + lane];
      acc.x = fmaf(vq, xv.x, acc.x);
      acc.y = fmaf(vq, xv.y, acc.y);
      acc.z = fmaf(vq, xv.z, acc.z);
      acc.w = fmaf(vq, xv.w, acc.w);
    }
  }
  size_t ii = (size_t)node*32 + lane;
  float dgn = dg[node];
  float4 xi = x4[ii];
  float4 r;
  r.x = alpha*(acc.x + dgn*xi.x);
  r.y = alpha*(acc.y + dgn*xi.y);
  r.z = alpha*(acc.z + dgn*xi.z);
  r.w = alpha*(acc.w + dgn*xi.w);
  if (z){
    float4 zi = ((const float4*)z)[ii];
    r.x = fmaf(beta, zi.x, r.x);
    r.y = fmaf(beta, zi.y, r.y);
    r.z = fmaf(beta, zi.z, r.z);
    r.w = fmaf(beta, zi.w, r.w);
  }
  ((float4*)y)[ii] = r;
}

__global__ __launch_bounds__(256) void spmm32_kernel(
    const int* __restrict__ ptrv, const int* __restrict__ srcs, const float* __restrict__ vals,
    const float* __restrict__ dg, const float* __restrict__ x, const float* __restrict__ z,
    float* __restrict__ y, int N, float alpha, float beta){
  int t = threadIdx.x;
  int g = t >> 3, lane = t & 7;
  int node = blockIdx.x*32 + g;
  if (node >= N) return;
  int e0 = ptrv[node], e1 = ptrv[node+1];
  const float4* x4 = (const float4*)x;
  float4 acc = make_float4(0.f,0.f,0.f,0.f);
  for (int eb = e0; eb < e1; eb += 8){
    int j = eb + lane;
    int s = srcs[j]; float v = vals[j];
    #pragma unroll
    for (int q = 0; q < 8; ++q){
      int   sq = __shfl(s, q, 8);
      float vq = __shfl(v, q, 8);
      float4 xv = x4[(size_t)sq*8 + lane];
      acc.x = fmaf(vq, xv.x, acc.x);
      acc.y = fmaf(vq, xv.y, acc.y);
      acc.z = fmaf(vq, xv.z, acc.z);
      acc.w = fmaf(vq, xv.w, acc.w);
    }
  }
  size_t ii = (size_t)node*8 + lane;
  float dgn = dg[node];
  float4 xi = x4[ii];
  float4 r;
  r.x = alpha*(acc.x + dgn*xi.x);
  r.y = alpha*(acc.y + dgn*xi.y);
  r.z = alpha*(acc.z + dgn*xi.z);
  r.w = alpha*(acc.w + dgn*xi.w);
  if (z){
    float4 zi = ((const float4*)z)[ii];
    r.x = fmaf(beta, zi.x, r.x);
    r.y = fmaf(beta, zi.y, r.y);
    r.z = fmaf(beta, zi.z, r.z);
    r.w = fmaf(beta, zi.w, r.w);
  }
  ((float4*)y)[ii] = r;
}

// ---------------- fused: th2 = 2*(L HRb) - HRb  +  gateB GRU update ---------
// (R6 version — LDS-staged Whh, proven passing.)
__global__ __launch_bounds__(256) void spmm_gateB_kernel(
    const int* __restrict__ ptrv, const int* __restrict__ srcs, const float* __restrict__ vals,
    const float* __restrict__ dg, const float* __restrict__ th1, const float* __restrict__ HRb,
    const float* __restrict__ Whh, const float* __restrict__ bhh,
    const float* __restrict__ Zb, const float* __restrict__ gx2b,
    float* __restrict__ H, int N){
  __shared__ float sp[8][3][128];
  __shared__ float sW[3072];
  int t = threadIdx.x;
  int g = t >> 5, lane = t & 31;
  int node = blockIdx.x*8 + g;
  bool valid = (node < N);
  if (!valid) node = N-1;
  for (int idx = t; idx < 3072; idx += 256) sW[idx] = Whh[idx];
  size_t ii = (size_t)node*32 + lane;
  const float4* x4 = (const float4*)th1;
  const float4* z4 = (const float4*)HRb;
  float4 Zv   = ((const float4*)Zb)[ii];
  float4 Gx   = ((const float4*)gx2b)[ii];
  float4 Hold = ((const float4*)H)[ii];
  float4 zi   = z4[ii];
  int e0 = ptrv[node], e1 = ptrv[node+1];
  float4 acc = make_float4(0.f,0.f,0.f,0.f);
  for (int eb = e0; eb < e1; eb += 8){
    int j = eb + (lane & 7);
    int s = srcs[j]; float v = vals[j];
    #pragma unroll
    for (int q = 0; q < 8; ++q){
      int   sq = __shfl(s, q, 32);
      float vq = __shfl(v, q, 32);
      float4 xv = x4[(size_t)sq*32 + lane];
      acc.x = fmaf(vq, xv.x, acc.x);
      acc.y = fmaf(vq, xv.y, acc.y);
      acc.z = fmaf(vq, xv.z, acc.z);
      acc.w = fmaf(vq, xv.w, acc.w);
    }
  }
  float dgn = dg[node];
  float4 xi = x4[ii];
  float4 p2;
  p2.x = 2.f*(acc.x + dgn*xi.x) - zi.x;
  p2.y = 2.f*(acc.y + dgn*xi.y) - zi.y;
  p2.z = 2.f*(acc.z + dgn*xi.z) - zi.z;
  p2.w = 2.f*(acc.w + dgn*xi.w) - zi.w;
  ((float4*)&sp[g][0][0])[lane] = zi;
  ((float4*)&sp[g][1][0])[lane] = xi;
  ((float4*)&sp[g][2][0])[lane] = p2;
  __syncthreads();
  int b = lane >> 5; (void)b;
  int bb8 = lane >> 3;
  const float4* W4 = (const float4*)sW;
  float4 bv = ((const float4*)bhh)[lane & 7];
  float gh0 = bv.x, gh1 = bv.y, gh2 = bv.z, gh3 = bv.w;
  #pragma unroll 1
  for (int k = 0; k < 3; ++k){
    const float* pk = &sp[g][k][bb8*32];
    #pragma unroll
    for (int o = 0; o < 32; o += 4){
      float4 pv = *reinterpret_cast<const float4*>(pk + o);
      #pragma unroll
      for (int oo = 0; oo < 4; ++oo){
        float p = reinterpret_cast<const float*>(&pv)[oo];
        float4 wv = W4[k*256 + (o+oo)*8 + (lane & 7)];
        gh0 = fmaf(p, wv.x, gh0);
        gh1 = fmaf(p, wv.y, gh1);
        gh2 = fmaf(p, wv.z, gh2);
        gh3 = fmaf(p, wv.w, gh3);
      }
    }
  }
  if (valid){
    float4 Hn;
    float Ht;
    Ht = tanhf(Gx.x + gh0); Hn.x = Zv.x*Hold.x + (1.f - Zv.x)*Ht;
    Ht = tanhf(Gx.y + gh1); Hn.y = Zv.y*Hold.y + (1.f - Zv.y)*Ht;
    Ht = tanhf(Gx.z + gh2); Hn.z = Zv.z*Hold.z + (1.f - Zv.z)*Ht;
    Ht = tanhf(Gx.w + gh3); Hn.w = Zv.w*Hold.w + (1.f - Zv.w)*Ht;
    ((float4*)H)[ii] = Hn;
  }
}

// ---------------- transpose layer-0 input ----------------
__global__ void transpose_x_kernel(const float* __restrict__ in, float* __restrict__ out,
                                   int N, int t){
  int idx = blockIdx.x*blockDim.x + threadIdx.x;   // over N*32
  if (idx >= N*32) return;
  int n = idx >> 5; int r = idx & 31; int b = r >> 3; int i = r & 7;
  out[idx] = in[(((size_t)b*12 + t)*N + n)*8 + i];
}

// ---------------- gate A (register-tiled GEMM, R5 version — proven) --------
template<int FIN>
__global__ __launch_bounds__(256) void gateA_kernel(
    const float* __restrict__ x0, const float* __restrict__ x1, const float* __restrict__ x2,
    const float* __restrict__ h0, const float* __restrict__ h1, const float* __restrict__ h2,
    const float* __restrict__ Wx, const float* __restrict__ bx,
    const float* __restrict__ Wh, const float* __restrict__ bh,
    float* __restrict__ Zb, float* __restrict__ gx2b, float* __restrict__ HRb, int M){
  int t = threadIdx.x;
  int h = t & 31, ty = t >> 5;
  int row0 = blockIdx.x*64 + ty*8;
  if (row0 >= M) return;
  bool full = (row0 + 8 <= M);

  float ag0[8]={0,0,0,0,0,0,0,0}, ag1[8]={0,0,0,0,0,0,0,0}, ag2[8]={0,0,0,0,0,0,0,0};
  float az[8]={0,0,0,0,0,0,0,0}, ar[8]={0,0,0,0,0,0,0,0};

  const float* xm[3] = {x0, x1, x2};
  const float* hm[3] = {h0, h1, h2};
  const int gstride = 3*FIN*32;

  #pragma unroll 1
  for (int k3 = 0; k3 < 3; ++k3){
    const float* Ak = xm[k3];
    const float* wb = Wx + k3*FIN*32 + h;
    #pragma unroll 1
    for (int k = 0; k < FIN; k += 4){
      float4 a4[8];
      #pragma unroll
      for (int r = 0; r < 8; ++r){
        int rr = row0 + r; if (!full && rr >= M) rr = M-1;
        a4[r] = *reinterpret_cast<const float4*>(Ak + (size_t)rr*FIN + k);
      }
      #pragma unroll
      for (int kk = 0; kk < 4; ++kk){
        float w0 = wb[(k+kk)*32];
        float w1 = wb[(size_t)gstride   + (k+kk)*32];
        float w2 = wb[(size_t)gstride*2 + (k+kk)*32];
        #pragma unroll
        for (int r = 0; r < 8; ++r){
          float av = reinterpret_cast<const float*>(&a4[r])[kk];
          ag0[r] = fmaf(av, w0, ag0[r]);
          ag1[r] = fmaf(av, w1, ag1[r]);
          ag2[r] = fmaf(av, w2, ag2[r]);
        }
      }
    }
  }

  #pragma unroll 1
  for (int k3 = 0; k3 < 3; ++k3){
    const float* Ak = hm[k3];
    const float* wbz = Wh + k3*1024 + h;          // Wh[0][k3][o][h]
    #pragma unroll 1
    for (int k = 0; k < 32; k += 4){
      float4 a4[8];
      #pragma unroll
      for (int r = 0; r < 8; ++r){
        int rr = row0 + r; if (!full && rr >= M) rr = M-1;
        a4[r] = *reinterpret_cast<const float4*>(Ak + (size_t)rr*32 + k);
      }
      #pragma unroll
      for (int kk = 0; kk < 4; ++kk){
        float wz = wbz[(k+kk)*32];
        float wr = wbz[3072 + (k+kk)*32];
        #pragma unroll
        for (int r = 0; r < 8; ++r){
          float av = reinterpret_cast<const float*>(&a4[r])[kk];
          az[r] = fmaf(av, wz, az[r]);
          ar[r] = fmaf(av, wr, ar[r]);
        }
      }
    }
  }

  float b0 = bx[h], b1 = bx[32+h], b2 = bx[64+h];
  float bz = bh[h], br = bh[32+h];
  #pragma unroll
  for (int r = 0; r < 8; ++r){
    int rr = row0 + r; if (rr >= M) break;
    float Z = sigmoidf_(ag0[r] + b0 + az[r] + bz);
    float R = sigmoidf_(ag1[r] + b1 + ar[r] + br);
    size_t ix = (size_t)rr*32 + h;
    Zb[ix]   = Z;
    gx2b[ix] = ag2[r] + b2;
    HRb[ix]  = h0[ix] * R;
  }
}

// ---------------- readout ----------------
__global__ void readout_kernel(const float* __restrict__ H1, const float* __restrict__ muW,
                               const float* __restrict__ mub, const float* __restrict__ sgW,
                               const float* __restrict__ sgb, float* __restrict__ outp, int N){
  int idx = blockIdx.x*blockDim.x + threadIdx.x;   // over 4*N
  if (idx >= 4*N) return;
  int b = idx / N, n = idx - b*N;
  const float* h = H1 + (size_t)n*128 + b*32;
  float m0 = mub[0], m1 = mub[1], s0 = sgb[0], s1 = sgb[1];
  #pragma unroll
  for (int o = 0; o < 32; ++o){
    float v = h[o];
    m0 = fmaf(v, muW[o*2+0], m0);
    m1 = fmaf(v, muW[o*2+1], m1);
    s0 = fmaf(v, sgW[o*2+0], s0);
    s1 = fmaf(v, sgW[o*2+1], s1);
  }
  size_t base = (size_t)(b*N + n)*2;
  outp[base]   = sigmoidf_(m0);
  outp[base+1] = sigmoidf_(m1);
  size_t sb = (size_t)8*N + base;
  outp[sb]   = (s0 > 15.f) ? s0 : log1pf(__expf(s0));
  outp[sb+1] = (s1 > 15.f) ? s1 : log1pf(__expf(s1));
}

__global__ void mean_kernel(const float* __restrict__ H1, float* __restrict__ mixsum, int N){
  int t = threadIdx.x;   // 128 = (b,o)
  int chunk = (N + gridDim.x - 1) / gridDim.x;
  int n0 = blockIdx.x*chunk, n1 = min(N, n0 + chunk);
  float acc = 0.f;
  for (int n = n0; n < n1; ++n) acc += H1[(size_t)n*128 + t];
  atomicAdd(mixsum + t, acc);
}

__global__ void softmax_kernel(const float* __restrict__ mixsum, float* __restrict__ outp,
                               float invN){
  __shared__ float v[128];
  __shared__ float e[128];
  int t = threadIdx.x; int b = t >> 5;
  float m = mixsum[t]*invN;
  v[t] = m; __syncthreads();
  float mx = -1e30f;
  for (int o = 0; o < 32; ++o) mx = fmaxf(mx, v[b*32 + o]);
  float ex = __expf(m - mx);
  e[t] = ex; __syncthreads();
  float s = 0.f;
  for (int o = 0; o < 32; ++o) s += e[b*32 + o];
  outp[t] = ex / s;
}

// ---------------------------------------------------------------------------

extern "C" void kernel_launch(void* const* d_in, const int* in_sizes, int n_in,
                              void* d_out, int out_size, void* d_ws, size_t ws_size,
                              hipStream_t stream){
  const float* in0  = (const float*)d_in[0];
  const void*  eidx = d_in[1];
  const float* ew   = (const float*)d_in[2];
  const float* Wx0  = (const float*)d_in[3];
  const float* Wh0  = (const float*)d_in[4];
  const float* bx0  = (const float*)d_in[5];
  const float* bh0  = (const float*)d_in[6];
  const float* Wx1  = (const float*)d_in[7];
  const float* Wh1  = (const float*)d_in[8];
  const float* bx1  = (const float*)d_in[9];
  const float* bh1  = (const float*)d_in[10];
  const float* muW  = (const float*)d_in[11];
  const float* mub  = (const float*)d_in[12];
  const float* sgW  = (const float*)d_in[13];
  const float* sgb  = (const float*)d_in[14];
  float* outp = (float*)d_out;

  const int N = in_sizes[0] / (4*12*8);
  const int E = in_sizes[1] / 2;
  const int M = 4*N;
  const int EP = E + 8*N;        // padded-edge capacity

  // ---- carve workspace (identical footprint to R5/R6: ~257MB, proven) ----
  char* w = (char*)d_ws;
  size_t off = 0;
  auto alloc = [&](size_t bytes)->void*{
    void* p = w + off;
    off += (bytes + 255) & ~(size_t)255;
    return p;
  };
  int*   row32   = (int*)  alloc((size_t)E*4);
  int*   col32   = (int*)  alloc((size_t)E*4);
  int*   csr_src = (int*)  alloc((size_t)EP*4);
  float* csr_val = (float*)alloc((size_t)EP*4);
  int*   ptrv    = (int*)  alloc((size_t)(N+1)*4);
  int*   cnt     = (int*)  alloc((size_t)N*4);
  int*   cnt2    = (int*)  alloc((size_t)N*4);
  float* deg     = (float*)alloc((size_t)N*4);
  float* dinv    = (float*)alloc((size_t)N*4);
  float* dgv     = (float*)alloc((size_t)N*4);
  int*   flag    = (int*)  alloc(256);
  float* mixsum  = (float*)alloc(512);
  float* xb0     = (float*)alloc((size_t)N*32*4);
  float* xb1     = (float*)alloc((size_t)N*128*4);  // basis(H0) cache T1 (written by L1)
  float* xb2     = (float*)alloc((size_t)N*128*4);  // basis(H0) cache T2
  float* th1     = (float*)alloc((size_t)N*128*4);  // h-basis scratch; low 12.8MB doubles as L0 x-basis
  float* th2     = (float*)alloc((size_t)N*128*4);
  float* Zb      = (float*)alloc((size_t)N*128*4);
  float* gx2b    = (float*)alloc((size_t)N*128*4);
  float* HRb     = (float*)alloc((size_t)N*128*4);
  float* H0      = (float*)alloc((size_t)N*128*4);
  float* H1      = (float*)alloc((size_t)N*128*4);
  // L0's 32-wide x-basis lives in th1's dead region (th1 not live across L0 gateA):
  float* xb1s = th1;                 // [N][32]
  float* xb2s = th1 + (size_t)N*32;  // [N][32]

  // ---- zero-init (ws is poisoned 0xAA before each call) ----
  hipMemsetAsync(flag,   0, 4, stream);
  hipMemsetAsync(deg,    0, (size_t)N*4, stream);
  hipMemsetAsync(cnt,    0, (size_t)N*4, stream);
  hipMemsetAsync(cnt2,   0, (size_t)N*4, stream);
  hipMemsetAsync(H0,     0, (size_t)N*128*4, stream);
  hipMemsetAsync(H1,     0, (size_t)N*128*4, stream);
  hipMemsetAsync(xb1,    0, (size_t)N*128*4, stream);  // basis(H0=0) = 0 at t=0
  hipMemsetAsync(xb2,    0, (size_t)N*128*4, stream);
  hipMemsetAsync(mixsum, 0, 512, stream);

  // ---- preprocessing: dtype detect, degrees, padded CSR build ----
  {
    int ndw = 4096;
    if (ndw > 2*E) ndw = 2*E;
    int nthread = ndw/2 + 1;
    detect_kernel<<<(nthread+255)/256, 256, 0, stream>>>((const unsigned*)eidx, ndw, flag);
  }
  convert_kernel<<<(E+255)/256, 256, 0, stream>>>(eidx, ew, E, flag, row32, col32, deg, cnt);
  node_prep_kernel<<<(N+255)/256, 256, 0, stream>>>(deg, dinv, dgv, N);
  scan_kernel<<<1, 1024, 0, stream>>>(cnt, ptrv, N);
  fill_kernel<<<(E+255)/256, 256, 0, stream>>>(row32, col32, ew, dinv, ptrv, cnt2,
                                               csr_src, csr_val, E);
  pad_kernel<<<(N+255)/256, 256, 0, stream>>>(cnt, ptrv, csr_src, csr_val, N);

  const int g128 = (N+7)/8;    // spmm128 / fused: 8 nodes / 256 threads
  const int g32  = (N+31)/32;  // spmm32: 32 nodes / 256 threads
  const int gG   = (M+63)/64;  // gateA: 64 rows / 256 threads

  for (int t = 0; t < 12; ++t){
    // ===== layer 0 (Fin=8); h-basis read from cache (xb1, xb2) =====
    transpose_x_kernel<<<(N*32+255)/256, 256, 0, stream>>>(in0, xb0, N, t);
    spmm32_kernel<<<g32,256,0,stream>>>(ptrv,csr_src,csr_val,dgv, xb0,nullptr,xb1s, N, 1.f, 0.f);
    spmm32_kernel<<<g32,256,0,stream>>>(ptrv,csr_src,csr_val,dgv, xb1s,xb0,  xb2s, N, 2.f,-1.f);
    gateA_kernel<8><<<gG,256,0,stream>>>(xb0,xb1s,xb2s, H0,xb1,xb2,
                                         Wx0,bx0, Wh0,bh0, Zb,gx2b,HRb, M);
    spmm128_kernel<<<g128,256,0,stream>>>(ptrv,csr_src,csr_val,dgv, HRb,nullptr,th1, N, 1.f, 0.f);
    spmm_gateB_kernel<<<g128,256,0,stream>>>(ptrv,csr_src,csr_val,dgv, th1,HRb,
                                             Wh0+6144, bh0+64, Zb,gx2b, H0, N);

    // ===== layer 1 (Fin=32, x = H0); x-basis -> cache (xb1, xb2) =====
    spmm128_kernel<<<g128,256,0,stream>>>(ptrv,csr_src,csr_val,dgv, H0,nullptr,xb1, N, 1.f, 0.f);
    spmm128_kernel<<<g128,256,0,stream>>>(ptrv,csr_src,csr_val,dgv, xb1,H0,   xb2, N, 2.f,-1.f);
    spmm128_kernel<<<g128,256,0,stream>>>(ptrv,csr_src,csr_val,dgv, H1,nullptr,th1, N, 1.f, 0.f);
    spmm128_kernel<<<g128,256,0,stream>>>(ptrv,csr_src,csr_val,dgv, th1,H1,   th2, N, 2.f,-1.f);
    gateA_kernel<32><<<gG,256,0,stream>>>(H0,xb1,xb2, H1,th1,th2,
                                          Wx1,bx1, Wh1,bh1, Zb,gx2b,HRb, M);
    spmm128_kernel<<<g128,256,0,stream>>>(ptrv,csr_src,csr_val,dgv, HRb,nullptr,th1, N, 1.f, 0.f);
    spmm_gateB_kernel<<<g128,256,0,stream>>>(ptrv,csr_src,csr_val,dgv, th1,HRb,
                                             Wh1+6144, bh1+64, Zb,gx2b, H1, N);
  }

  // ---- readout ----
  readout_kernel<<<(4*N+255)/256, 256, 0, stream>>>(H1, muW, mub, sgW, sgb, outp, N);
  mean_kernel<<<256, 128, 0, stream>>>(H1, mixsum, N);
  softmax_kernel<<<1, 128, 0, stream>>>(mixsum, outp + (size_t)16*N, 1.0f/(float)N);
}